// Round 4
// baseline (1240.956 us; speedup 1.0000x reference)
//
#include <hip/hip_runtime.h>
#include <hip/hip_cooperative_groups.h>
#include <stdint.h>

namespace cg = cooperative_groups;

// ---------- helpers ----------
typedef __attribute__((ext_vector_type(8))) short bf16x8;
typedef __attribute__((ext_vector_type(4))) float f32x4;

__device__ __forceinline__ float bf16lo_to_f(uint32_t u) { return __uint_as_float(u << 16); }
__device__ __forceinline__ float bf16hi_to_f(uint32_t u) { return __uint_as_float(u & 0xffff0000u); }
__device__ __forceinline__ uint16_t f_to_bf16(float f) {
    uint32_t u = __float_as_uint(f);
    uint32_t r = u + 0x7fff + ((u >> 16) & 1);   // round-to-nearest-even
    return (uint16_t)(r >> 16);
}

// Layouts:
//  Txb : bf16 [5][N+1][128] -- GEMM A operand mirror (slot-major, 256B rows)
//  Txq : int8 [5][N+1][128] -- gather state (slot-major, 128B rows = 1 cache line)
//  mS  : f32  [5][N+1]      -- per-row quant scale; sentinel row N = 0
//  ew  : uint2 [E + 8N]     -- {col*128 (byte offset into int8 slot), w f32}; pad w=0

#define BINCH 4096

// =========================================================================
// Standalone (fallback) preprocessing kernels — proven round-2 versions
// =========================================================================
__global__ void __launch_bounds__(256) k_bhist(const int* __restrict__ row,
                                               int* __restrict__ bhist, int E) {
    __shared__ int sh[256];
    int t = threadIdx.x;
    sh[t] = 0;
    __syncthreads();
    int stride = gridDim.x * blockDim.x;
    for (int e = blockIdx.x * blockDim.x + t; e < E; e += stride)
        atomicAdd(&sh[row[e] >> 8], 1);
    __syncthreads();
    if (sh[t]) atomicAdd(&bhist[t], sh[t]);
}

__global__ void k_bscan(const int* __restrict__ bhist, int* __restrict__ gbase,
                        int* __restrict__ gcur, float* __restrict__ mS, int nbk, int N) {
    __shared__ int sh[256];
    int t = threadIdx.x;
    int v = t < nbk ? bhist[t] : 0;
    sh[t] = v;
    __syncthreads();
    for (int o = 1; o < 256; o <<= 1) {
        int u = (t >= o) ? sh[t - o] : 0;
        __syncthreads();
        sh[t] += u;
        __syncthreads();
    }
    gbase[t] = sh[t] - v;
    gcur[t] = sh[t] - v;
    if (t == 255) gbase[256] = sh[255];
    if (t < 5) mS[(size_t)t * (N + 1) + N] = 0.f;
}

__global__ void __launch_bounds__(256) k_bin(const int* __restrict__ row,
        const int* __restrict__ col, int* __restrict__ gcur,
        uint32_t* __restrict__ bout, int E) {
    __shared__ uint32_t stage[BINCH];
    __shared__ int hist[256], hscan[256], hcur[256], gofs[256];
    int t = threadIdx.x;
    int e0 = blockIdx.x * BINCH;
    int ecnt = min(BINCH, E - e0);
    hist[t] = 0;
    __syncthreads();
    for (int i = t; i < ecnt; i += 256)
        atomicAdd(&hist[row[e0 + i] >> 8], 1);
    __syncthreads();
    int v = hist[t];
    hscan[t] = v;
    __syncthreads();
    for (int o = 1; o < 256; o <<= 1) {
        int u = (t >= o) ? hscan[t - o] : 0;
        __syncthreads();
        hscan[t] += u;
        __syncthreads();
    }
    hcur[t] = hscan[t] - v;
    __syncthreads();
    for (int i = t; i < ecnt; i += 256) {
        int r = row[e0 + i];
        int p = atomicAdd(&hcur[r >> 8], 1);
        stage[p] = (uint32_t)(r & 255) | ((uint32_t)col[e0 + i] << 8);
    }
    __syncthreads();
    if (v > 0) gofs[t] = atomicAdd(&gcur[t], v);
    __syncthreads();
    for (int i = t; i < ecnt; i += 256) {
        int lo = 0, hi = 255;
        while (lo < hi) { int mid = (lo + hi) >> 1; if (hscan[mid] > i) hi = mid; else lo = mid + 1; }
        int b = lo;
        int local = i - (hscan[b] - hist[b]);
        bout[gofs[b] + local] = stage[i];
    }
}

__global__ void __launch_bounds__(256) k_deg2(const uint32_t* __restrict__ bout,
        const int* __restrict__ gbase, int* __restrict__ deg,
        int* __restrict__ psum, int N) {
    __shared__ int cnt[256];
    __shared__ int red[256];
    int t = threadIdx.x, b = blockIdx.x;
    cnt[t] = 0;
    __syncthreads();
    int s = gbase[b], epos = gbase[b + 1];
    for (int i = s + t; i < epos; i += 256)
        atomicAdd(&cnt[bout[i] & 255], 1);
    __syncthreads();
    int n = b * 256 + t;
    int d = cnt[t];
    if (n < N) deg[n] = d;
    red[t] = (n < N) ? ((d + 7) & ~7) : 0;
    __syncthreads();
    for (int o = 128; o > 0; o >>= 1) {
        if (t < o) red[t] += red[t + o];
        __syncthreads();
    }
    if (t == 0) psum[b] = red[0];
}

__global__ void k_offs(const int* __restrict__ deg, const int* __restrict__ psum,
                       int* __restrict__ offs,
                       const int* __restrict__ batch, const float* __restrict__ lam,
                       float* __restrict__ dis, float* __restrict__ diag,
                       int N, int nb) {
    __shared__ int pre[256];
    __shared__ int sh[256];
    int t = threadIdx.x, b = blockIdx.x;
    pre[t] = (t < b) ? psum[t] : 0;
    __syncthreads();
    for (int o = 128; o > 0; o >>= 1) {
        if (t < o) pre[t] += pre[t + o];
        __syncthreads();
    }
    int base = pre[0];
    __syncthreads();
    int idx = b * 256 + t;
    int d = idx < N ? deg[idx] : 0;
    int v = (d + 7) & ~7;
    sh[t] = v;
    __syncthreads();
    for (int o = 1; o < 256; o <<= 1) {
        int u = (t >= o) ? sh[t - o] : 0;
        __syncthreads();
        sh[t] += u;
        __syncthreads();
    }
    if (idx < N) {
        offs[idx] = base + sh[t] - v;
        dis[idx] = d > 0 ? rsqrtf((float)d) : 0.f;
        diag[idx] = 2.f / lam[batch[idx]] - 1.f;
    }
    if (b == nb - 1 && t == 255) offs[N] = base + sh[255];
}

__global__ void __launch_bounds__(256) k_ew(const uint32_t* __restrict__ bout,
        const int* __restrict__ gbase, const int* __restrict__ offs,
        const float* __restrict__ dis, const float* __restrict__ diag,
        uint2* __restrict__ ew, int N) {
    __shared__ int cur[256];
    __shared__ float srw[256];
    int t = threadIdx.x, b = blockIdx.x;
    int n = b * 256 + t;
    int o0 = n < N ? offs[n] : 0;
    cur[t] = o0;
    srw[t] = (n < N) ? (-dis[n] * (diag[n] + 1.0f)) : 0.f;
    __syncthreads();
    int s = gbase[b], epos = gbase[b + 1];
    for (int i = s + t; i < epos; i += 256) {
        uint32_t v = bout[i];
        int r = (int)(v & 255u);
        int c = (int)(v >> 8);
        int p = atomicAdd(&cur[r], 1);
        float w = srw[r] * dis[c];
        ew[p] = make_uint2((uint32_t)c << 7, __float_as_uint(w));
    }
    __syncthreads();
    if (n < N) {
        int e = cur[t];
        int pe = o0 + ((e - o0 + 7) & ~7);
        uint2 pad = make_uint2((uint32_t)N << 7, 0u);
        for (int p = e; p < pe; p++) ew[p] = pad;
    }
}

__global__ void k_prepw(const float* __restrict__ W1, uint16_t* __restrict__ Wt1,
                        const float* __restrict__ W2, uint16_t* __restrict__ Wt2) {
    int i = blockIdx.x * blockDim.x + threadIdx.x;
    const float* W = W1; uint16_t* Wt = Wt1;
    if (i >= 128 * 640) { i -= 128 * 640; W = W2; Wt = Wt2; }
    int o = i / 640, kk = i % 640;
    Wt[(size_t)o * 640 + kk] = f_to_bf16(W[(size_t)kk * 128 + o]);
}

__global__ void __launch_bounds__(256) k_castx(const float* __restrict__ x,
        uint16_t* __restrict__ Txb, int8_t* __restrict__ Txq,
        float* __restrict__ mS, int N) {
    int n = (blockIdx.x * blockDim.x + threadIdx.x) >> 6;
    int lane = threadIdx.x & 63;
    if (n >= N) return;
    float2 v = ((const float2*)x)[(size_t)n * 64 + lane];
    uint32_t p = (uint32_t)f_to_bf16(v.x) | ((uint32_t)f_to_bf16(v.y) << 16);
    ((uint32_t*)Txb)[(size_t)n * 64 + lane] = p;
    float m = fmaxf(fabsf(v.x), fabsf(v.y));
    for (int o = 1; o < 64; o <<= 1) m = fmaxf(m, __shfl_xor(m, o));
    float inv = m > 0.f ? 127.f / m : 0.f;
    int qx = (int)rintf(v.x * inv), qy = (int)rintf(v.y * inv);
    *(uint16_t*)(Txq + (size_t)n * 128 + 2 * lane) = (uint16_t)((qx & 0xff) | ((qy & 0xff) << 8));
    if (lane == 0) mS[n] = m > 0.f ? m * (1.f / 127.f) : 0.f;
}

// =========================================================================
// k_pre: ONE cooperative kernel for the whole preprocessing chain + castx.
// =========================================================================
__global__ void __launch_bounds__(256) k_pre(
        const float* __restrict__ x,
        const int* __restrict__ row, const int* __restrict__ col,
        const int* __restrict__ batch, const float* __restrict__ lam,
        const float* __restrict__ W1, uint16_t* __restrict__ Wt1,
        const float* __restrict__ W2, uint16_t* __restrict__ Wt2,
        int* __restrict__ bhist, int* __restrict__ gbase, int* __restrict__ gcur,
        uint32_t* __restrict__ bout, int* __restrict__ deg, int* __restrict__ psum,
        int* __restrict__ offs, float* __restrict__ dis, float* __restrict__ diag,
        uint2* __restrict__ ew, float* __restrict__ mS,
        uint16_t* __restrict__ Txb, int8_t* __restrict__ Txq,
        int E, int N, int nb, int nchunks) {
    __shared__ uint32_t shb[5120];            // 20KB union for all phases
    cg::grid_group grid = cg::this_grid();
    int t = threadIdx.x, b = blockIdx.x;
    int gstride = gridDim.x * 256;

    // ---- phase 1a: bhist ----
    {
        int* sh = (int*)shb;
        sh[t] = 0;
        __syncthreads();
        for (int e = b * 256 + t; e < E; e += gstride)
            atomicAdd(&sh[row[e] >> 8], 1);
        __syncthreads();
        if (sh[t]) atomicAdd(&bhist[t], sh[t]);
    }
    // ---- phase 1b: prepw ----
    for (int i = b * 256 + t; i < 2 * 128 * 640; i += gstride) {
        int ii = i;
        const float* W = W1; uint16_t* Wt = Wt1;
        if (ii >= 128 * 640) { ii -= 128 * 640; W = W2; Wt = Wt2; }
        int o = ii / 640, kk = ii % 640;
        Wt[(size_t)o * 640 + kk] = f_to_bf16(W[(size_t)kk * 128 + o]);
    }
    // ---- phase 1c: castx ----
    {
        int lane = t & 63;
        int gw = b * 4 + (t >> 6);
        int tw = gridDim.x * 4;
        for (int n = gw; n < N; n += tw) {
            float2 v = ((const float2*)x)[(size_t)n * 64 + lane];
            uint32_t p = (uint32_t)f_to_bf16(v.x) | ((uint32_t)f_to_bf16(v.y) << 16);
            ((uint32_t*)Txb)[(size_t)n * 64 + lane] = p;
            float m = fmaxf(fabsf(v.x), fabsf(v.y));
            for (int o = 1; o < 64; o <<= 1) m = fmaxf(m, __shfl_xor(m, o));
            float inv = m > 0.f ? 127.f / m : 0.f;
            int qx = (int)rintf(v.x * inv), qy = (int)rintf(v.y * inv);
            *(uint16_t*)(Txq + (size_t)n * 128 + 2 * lane) =
                (uint16_t)((qx & 0xff) | ((qy & 0xff) << 8));
            if (lane == 0) mS[n] = m > 0.f ? m * (1.f / 127.f) : 0.f;
        }
    }
    grid.sync();

    // ---- phase 2: bscan on block 0 + mS sentinels ----
    if (b == 0) {
        int* sh = (int*)shb;
        int v = bhist[t];
        sh[t] = v;
        __syncthreads();
        for (int o = 1; o < 256; o <<= 1) {
            int u = (t >= o) ? sh[t - o] : 0;
            __syncthreads();
            sh[t] += u;
            __syncthreads();
        }
        gbase[t] = sh[t] - v;
        gcur[t] = sh[t] - v;
        if (t == 255) gbase[256] = sh[255];
        if (t < 5) mS[(size_t)t * (N + 1) + N] = 0.f;
    }
    grid.sync();

    // ---- phase 3: bin ----
    if (b < nchunks) {
        uint32_t* stage = shb;
        int* hist  = (int*)(shb + 4096);
        int* hscan = (int*)(shb + 4352);
        int* hcur  = (int*)(shb + 4608);
        int* gofs  = (int*)(shb + 4864);
        int e0 = b * BINCH;
        int ecnt = min(BINCH, E - e0);
        hist[t] = 0;
        __syncthreads();
        for (int i = t; i < ecnt; i += 256)
            atomicAdd(&hist[row[e0 + i] >> 8], 1);
        __syncthreads();
        int v = hist[t];
        hscan[t] = v;
        __syncthreads();
        for (int o = 1; o < 256; o <<= 1) {
            int u = (t >= o) ? hscan[t - o] : 0;
            __syncthreads();
            hscan[t] += u;
            __syncthreads();
        }
        hcur[t] = hscan[t] - v;
        __syncthreads();
        for (int i = t; i < ecnt; i += 256) {
            int r = row[e0 + i];
            int p = atomicAdd(&hcur[r >> 8], 1);
            stage[p] = (uint32_t)(r & 255) | ((uint32_t)col[e0 + i] << 8);
        }
        __syncthreads();
        if (v > 0) gofs[t] = atomicAdd(&gcur[t], v);
        __syncthreads();
        for (int i = t; i < ecnt; i += 256) {
            int lo = 0, hi = 255;
            while (lo < hi) { int mid = (lo + hi) >> 1; if (hscan[mid] > i) hi = mid; else lo = mid + 1; }
            int bb = lo;
            int local = i - (hscan[bb] - hist[bb]);
            bout[gofs[bb] + local] = stage[i];
        }
    }
    grid.sync();

    // ---- phase 4: deg2 + psum ----
    if (b < nb) {
        int* cnt = (int*)shb;
        int* red = (int*)(shb + 256);
        cnt[t] = 0;
        __syncthreads();
        int s = gbase[b], epos = gbase[b + 1];
        for (int i = s + t; i < epos; i += 256)
            atomicAdd(&cnt[bout[i] & 255], 1);
        __syncthreads();
        int n = b * 256 + t;
        int d = cnt[t];
        if (n < N) deg[n] = d;
        red[t] = (n < N) ? ((d + 7) & ~7) : 0;
        __syncthreads();
        for (int o = 128; o > 0; o >>= 1) {
            if (t < o) red[t] += red[t + o];
            __syncthreads();
        }
        if (t == 0) psum[b] = red[0];
    }
    grid.sync();

    // ---- phase 5: offs + dis + diag ----
    if (b < nb) {
        int* pre = (int*)shb;
        int* sh2 = (int*)(shb + 256);
        pre[t] = (t < b) ? psum[t] : 0;
        __syncthreads();
        for (int o = 128; o > 0; o >>= 1) {
            if (t < o) pre[t] += pre[t + o];
            __syncthreads();
        }
        int base = pre[0];
        __syncthreads();
        int idx = b * 256 + t;
        int d = idx < N ? deg[idx] : 0;
        int v = (d + 7) & ~7;
        sh2[t] = v;
        __syncthreads();
        for (int o = 1; o < 256; o <<= 1) {
            int u = (t >= o) ? sh2[t - o] : 0;
            __syncthreads();
            sh2[t] += u;
            __syncthreads();
        }
        if (idx < N) {
            offs[idx] = base + sh2[t] - v;
            dis[idx] = d > 0 ? rsqrtf((float)d) : 0.f;
            diag[idx] = 2.f / lam[batch[idx]] - 1.f;
        }
        if (b == nb - 1 && t == 255) offs[N] = base + sh2[255];
    }
    grid.sync();

    // ---- phase 6: ew scatter + padding ----
    if (b < nb) {
        int* cur = (int*)shb;
        float* srw = (float*)(shb + 256);
        int n = b * 256 + t;
        int o0 = n < N ? offs[n] : 0;
        cur[t] = o0;
        srw[t] = (n < N) ? (-dis[n] * (diag[n] + 1.0f)) : 0.f;
        __syncthreads();
        int s = gbase[b], epos = gbase[b + 1];
        for (int i = s + t; i < epos; i += 256) {
            uint32_t v = bout[i];
            int r = (int)(v & 255u);
            int c = (int)(v >> 8);
            int p = atomicAdd(&cur[r], 1);
            float w = srw[r] * dis[c];
            ew[p] = make_uint2((uint32_t)c << 7, __float_as_uint(w));
        }
        __syncthreads();
        if (n < N) {
            int e = cur[t];
            int pe = o0 + ((e - o0 + 7) & ~7);
            uint2 pad = make_uint2((uint32_t)N << 7, 0u);
            for (int p = e; p < pe; p++) ew[p] = pad;
        }
    }
}

// =========================================================================
// lhat node body (round-2 proven)
// =========================================================================
__device__ __forceinline__ void lhat_node(int n, int lane,
        int8_t* __restrict__ Txq, uint16_t* __restrict__ Txb,
        float* __restrict__ mS, const uint2* __restrict__ ew, int N,
        int beg, int end, float dgn,
        int src, int dst, int prev, float alpha, bool use_prev) {
    int h = lane >> 5, g = lane & 31;
    size_t sq = (size_t)(N + 1) * 128;
    const int8_t* srcq = Txq + (size_t)src * sq;
    const float* msrc = mS + (size_t)src * (N + 1);
    uint32_t lo4 = (uint32_t)g * 4;
    const uint2* ewh = ew + h;
    float a0 = 0.f, a1 = 0.f, a2 = 0.f, a3 = 0.f;
    if (beg < end) {
        uint2 ep[4];
#pragma unroll
        for (int p = 0; p < 4; p++) ep[p] = ewh[beg + 2 * p];
        int e = beg;
        while (true) {
            uint32_t q[4]; float mm[4], wv[4];
#pragma unroll
            for (int p = 0; p < 4; p++) {
                uint32_t co = ep[p].x;
                wv[p] = __uint_as_float(ep[p].y);
                q[p] = *(const uint32_t*)(srcq + co + lo4);
                mm[p] = *(const float*)((const char*)msrc + (co >> 5));   // col*4
            }
            int e2 = e + 8;
            bool more = e2 < end;
            uint2 epn[4];
            if (more) {
#pragma unroll
                for (int p = 0; p < 4; p++) epn[p] = ewh[e2 + 2 * p];
            }
#pragma unroll
            for (int p = 0; p < 4; p++) {
                float f = wv[p] * mm[p];
                a0 = fmaf(f, (float)(int)(int8_t)(q[p] & 0xff), a0);
                a1 = fmaf(f, (float)(int)(int8_t)((q[p] >> 8) & 0xff), a1);
                a2 = fmaf(f, (float)(int)(int8_t)((q[p] >> 16) & 0xff), a2);
                a3 = fmaf(f, (float)(int)(int8_t)(q[p] >> 24), a3);
            }
            if (!more) break;
            e = e2;
#pragma unroll
            for (int p = 0; p < 4; p++) ep[p] = epn[p];
        }
    }
    a0 += __shfl_xor(a0, 32);
    a1 += __shfl_xor(a1, 32);
    a2 += __shfl_xor(a2, 32);
    a3 += __shfl_xor(a3, 32);
    uint32_t rq = (uint32_t)n * 128 + lo4;
    uint32_t qs = *(const uint32_t*)(srcq + rq);
    float ssc = msrc[n] * dgn;
    a0 = fmaf(ssc, (float)(int)(int8_t)(qs & 0xff), a0);
    a1 = fmaf(ssc, (float)(int)(int8_t)((qs >> 8) & 0xff), a1);
    a2 = fmaf(ssc, (float)(int)(int8_t)((qs >> 16) & 0xff), a2);
    a3 = fmaf(ssc, (float)(int)(int8_t)(qs >> 24), a3);
    float f0 = alpha * a0, f1 = alpha * a1, f2 = alpha * a2, f3 = alpha * a3;
    if (use_prev) {
        uint32_t qp = *(const uint32_t*)(Txq + (size_t)prev * sq + rq);
        float sp = mS[(size_t)prev * (N + 1) + n];
        f0 = fmaf(-sp, (float)(int)(int8_t)(qp & 0xff), f0);
        f1 = fmaf(-sp, (float)(int)(int8_t)((qp >> 8) & 0xff), f1);
        f2 = fmaf(-sp, (float)(int)(int8_t)((qp >> 16) & 0xff), f2);
        f3 = fmaf(-sp, (float)(int)(int8_t)(qp >> 24), f3);
    }
    if (h == 0) {
        uint2 pk;
        pk.x = (uint32_t)f_to_bf16(f0) | ((uint32_t)f_to_bf16(f1) << 16);
        pk.y = (uint32_t)f_to_bf16(f2) | ((uint32_t)f_to_bf16(f3) << 16);
        *(uint2*)(Txb + (size_t)dst * (size_t)(N + 1) * 128 + (size_t)n * 128 + g * 4) = pk;
    }
    float m = fmaxf(fmaxf(fabsf(f0), fabsf(f1)), fmaxf(fabsf(f2), fabsf(f3)));
#pragma unroll
    for (int o = 1; o < 32; o <<= 1) m = fmaxf(m, __shfl_xor(m, o));
    float inv = m > 0.f ? 127.f / m : 0.f;
    if (h == 0) {
        int q0 = (int)rintf(f0 * inv), q1 = (int)rintf(f1 * inv);
        int q2 = (int)rintf(f2 * inv), q3 = (int)rintf(f3 * inv);
        uint32_t pkq = (uint32_t)(q0 & 0xff) | ((uint32_t)(q1 & 0xff) << 8) |
                       ((uint32_t)(q2 & 0xff) << 16) | ((uint32_t)(q3 & 0xff) << 24);
        *(uint32_t*)(Txq + (size_t)dst * sq + rq) = pkq;
    }
    if (lane == 0) mS[(size_t)dst * (N + 1) + n] = m * (1.f / 127.f);
}

// standalone lhat (fallback path)
__global__ void __launch_bounds__(256) k_lhat(
        int8_t* __restrict__ Txq, uint16_t* __restrict__ Txb,
        float* __restrict__ mS,
        const int* __restrict__ offs, const uint2* __restrict__ ew,
        const float* __restrict__ diag, int N,
        int src, int dst, int prev, float alpha, int use_prev) {
    int n = (blockIdx.x * blockDim.x + threadIdx.x) >> 6;
    int lane = threadIdx.x & 63;
    if (n >= N) return;
    lhat_node(n, lane, Txq, Txb, mS, ew, N, offs[n], offs[n + 1], diag[n],
              src, dst, prev, alpha, use_prev != 0);
}

// =========================================================================
// k_layer: cooperative = 4 lhat passes with grid.sync between.
// =========================================================================
__global__ void __launch_bounds__(256, 4) k_layer(
        int8_t* __restrict__ Txq, uint16_t* __restrict__ Txb,
        float* __restrict__ mS,
        const int* __restrict__ offs, const uint2* __restrict__ ew,
        const float* __restrict__ diag, int N) {
    cg::grid_group grid = cg::this_grid();
    int lane = threadIdx.x & 63;
    int gw = blockIdx.x * 4 + (threadIdx.x >> 6);
    int tw = gridDim.x * 4;

#define LHAT_PHASE(SRC, DST, PRV, ALPHA, UP)                                   \
    {                                                                          \
        int n = gw, pb = 0, pe = 0; float pd = 0.f;                            \
        if (n < N) { pb = offs[n]; pe = offs[n + 1]; pd = diag[n]; }           \
        while (n < N) {                                                        \
            int beg = pb, ee = pe; float dg = pd;                              \
            int n2 = n + tw;                                                   \
            if (n2 < N) { pb = offs[n2]; pe = offs[n2 + 1]; pd = diag[n2]; }   \
            lhat_node(n, lane, Txq, Txb, mS, ew, N, beg, ee, dg,               \
                      SRC, DST, PRV, ALPHA, UP);                               \
            n = n2;                                                            \
        }                                                                      \
    }

    LHAT_PHASE(0, 1, 0, 1.f, false);
    grid.sync();
    LHAT_PHASE(1, 2, 0, 2.f, true);
    grid.sync();
    LHAT_PHASE(2, 3, 1, 2.f, true);
    grid.sync();
    LHAT_PHASE(3, 4, 2, 2.f, true);
#undef LHAT_PHASE
}

// ---------- GEMM: relu(A[M,640] @ Wt^T + bias), bf16 MFMA, BM=128 tile ----------
#define BM 128
#define BK 64
#define LDT 72
#define LDC 132

__global__ void __launch_bounds__(256) k_gemm(
        const uint16_t* __restrict__ A, size_t sstride,
        const uint16_t* __restrict__ Bt,
        const float* __restrict__ bias,
        uint16_t* __restrict__ out2b,
        int8_t* __restrict__ out2q,
        float* __restrict__ msOut,
        float* __restrict__ pooled,
        const int* __restrict__ batch,
        int M, int Kdim) {
    __shared__ uint16_t smem[BM * LDT + 128 * LDT];
    uint16_t* As = smem;
    uint16_t* Bs = smem + BM * LDT;
    uint16_t* Ct = smem;
    int t = threadIdx.x;
    int w = t >> 6, lane = t & 63;
    int row0 = blockIdx.x * BM;
    int mrow = (w >> 1) * 64, ncol = (w & 1) * 64;

    int ar[4], akc[4];
#pragma unroll
    for (int rep = 0; rep < 4; rep++) {
        int d = rep * 256 + t;
        ar[rep] = d >> 3; akc[rep] = d & 7;
    }

    f32x4 acc[4][4];
#pragma unroll
    for (int i = 0; i < 4; i++)
#pragma unroll
        for (int j = 0; j < 4; j++) acc[i][j] = (f32x4){0.f, 0.f, 0.f, 0.f};

    bf16x8 pa[4], pb[4];
#pragma unroll
    for (int rep = 0; rep < 4; rep++) {
        int grow = row0 + ar[rep];
        int kk = akc[rep] * 8;
        bf16x8 va = {0, 0, 0, 0, 0, 0, 0, 0};
        if (grow < M)
            va = *(const bf16x8*)(A + (size_t)(kk >> 7) * sstride + (size_t)grow * 128 + (kk & 127));
        pa[rep] = va;
        pb[rep] = *(const bf16x8*)(Bt + (size_t)ar[rep] * Kdim + kk);
    }

    for (int k0 = 0; k0 < Kdim; k0 += BK) {
#pragma unroll
        for (int rep = 0; rep < 4; rep++) {
            *(bf16x8*)(&As[ar[rep] * LDT + akc[rep] * 8]) = pa[rep];
            *(bf16x8*)(&Bs[ar[rep] * LDT + akc[rep] * 8]) = pb[rep];
        }
        __syncthreads();
        int kn = k0 + BK;
        if (kn < Kdim) {
#pragma unroll
            for (int rep = 0; rep < 4; rep++) {
                int grow = row0 + ar[rep];
                int kk = kn + akc[rep] * 8;
                bf16x8 va = {0, 0, 0, 0, 0, 0, 0, 0};
                if (grow < M)
                    va = *(const bf16x8*)(A + (size_t)(kk >> 7) * sstride + (size_t)grow * 128 + (kk & 127));
                pa[rep] = va;
                pb[rep] = *(const bf16x8*)(Bt + (size_t)ar[rep] * Kdim + kk);
            }
        }
#pragma unroll
        for (int ks = 0; ks < BK; ks += 32) {
            bf16x8 af[4], bfr[4];
#pragma unroll
            for (int i = 0; i < 4; i++) {
                int r = mrow + i * 16 + (lane & 15);
                af[i] = *(const bf16x8*)(&As[r * LDT + ks + (lane >> 4) * 8]);
            }
#pragma unroll
            for (int j = 0; j < 4; j++) {
                int c = ncol + j * 16 + (lane & 15);
                bfr[j] = *(const bf16x8*)(&Bs[c * LDT + ks + (lane >> 4) * 8]);
            }
#pragma unroll
            for (int i = 0; i < 4; i++)
#pragma unroll
                for (int j = 0; j < 4; j++)
                    acc[i][j] = __builtin_amdgcn_mfma_f32_16x16x32_bf16(af[i], bfr[j], acc[i][j], 0, 0, 0);
        }
        __syncthreads();
    }

#pragma unroll
    for (int j = 0; j < 4; j++) {
        int c = ncol + j * 16 + (lane & 15);
        float bv = bias[c];
#pragma unroll
        for (int i = 0; i < 4; i++) {
            int rloc = mrow + i * 16 + (lane >> 4) * 4;
#pragma unroll
            for (int r = 0; r < 4; r++) {
                float v = acc[i][j][r] + bv;
                v = v > 0.f ? v : 0.f;
                Ct[(rloc + r) * LDC + c] = f_to_bf16(v);
            }
        }
    }
    __syncthreads();

    if (out2b) {
#pragma unroll
        for (int rep = 0; rep < 8; rep++) {
            int d = rep * 256 + t;
            int r = d >> 4, c8 = (d & 15) * 8;
            int grow = row0 + r;
            if (grow < M) {
                bf16x8 v = *(const bf16x8*)(&Ct[r * LDC + c8]);
                *(bf16x8*)(out2b + (size_t)grow * 128 + c8) = v;
            }
        }
    }
    if (out2q) {
        int r = t >> 1, half = t & 1;
        int grow = row0 + r;
        float vmax = 0.f;
        for (int j = 0; j < 32; j++) {
            uint32_t u = *(const uint32_t*)(&Ct[r * LDC + half * 64 + j * 2]);
            vmax = fmaxf(vmax, fmaxf(fabsf(bf16lo_to_f(u)), fabsf(bf16hi_to_f(u))));
        }
        vmax = fmaxf(vmax, __shfl_xor(vmax, 1));
        if (grow < M) {
            float inv = vmax > 0.f ? 127.f / vmax : 0.f;
            for (int j0 = 0; j0 < 16; j0++) {
                uint32_t u0 = *(const uint32_t*)(&Ct[r * LDC + half * 64 + j0 * 4]);
                uint32_t u1 = *(const uint32_t*)(&Ct[r * LDC + half * 64 + j0 * 4 + 2]);
                int q0 = (int)rintf(bf16lo_to_f(u0) * inv);
                int q1 = (int)rintf(bf16hi_to_f(u0) * inv);
                int q2 = (int)rintf(bf16lo_to_f(u1) * inv);
                int q3 = (int)rintf(bf16hi_to_f(u1) * inv);
                uint32_t pk = (uint32_t)(q0 & 0xff) | ((uint32_t)(q1 & 0xff) << 8) |
                              ((uint32_t)(q2 & 0xff) << 16) | ((uint32_t)(q3 & 0xff) << 24);
                *(uint32_t*)(out2q + (size_t)grow * 128 + half * 64 + j0 * 4) = pk;
            }
            if (half == 0) msOut[grow] = vmax * (1.f / 127.f);
        }
    }
    if (pooled) {
        int f = t & 127, r0 = (t >> 7) * 64;
        float accp = 0.f;
        int curb = -1;
        for (int r = r0; r < r0 + 64; ++r) {
            int grow = row0 + r;
            if (grow >= M) break;
            int b = batch[grow];
            if (b != curb) {
                if (curb >= 0) atomicAdd(&pooled[curb * 128 + f], accp);
                accp = 0.f; curb = b;
            }
            accp += __uint_as_float(((uint32_t)Ct[r * LDC + f]) << 16);
        }
        if (curb >= 0) atomicAdd(&pooled[curb * 128 + f], accp);
    }
}

// ---------- final linear ----------
__global__ void k_final(const float* __restrict__ pooled, const int* __restrict__ batch,
                        const float* __restrict__ Wlin, const float* __restrict__ blin,
                        float* __restrict__ out, int N, int B_, int C_) {
    __shared__ int cnt[64];
    int t = threadIdx.x;
    if (t < B_) {
        auto lb = [&](int v) {
            int lo = 0, hi = N;
            while (lo < hi) {
                int mid = (lo + hi) >> 1;
                if (batch[mid] < v) lo = mid + 1; else hi = mid;
            }
            return lo;
        };
        cnt[t] = lb(t + 1) - lb(t);
    }
    __syncthreads();
    if (t < B_ * C_) {
        int b = t / C_, c = t % C_;
        float inv = 1.f / fmaxf((float)cnt[b], 1.f);
        float acc = blin[c];
        for (int f = 0; f < 128; ++f) acc += pooled[b * 128 + f] * inv * Wlin[f * C_ + c];
        out[t] = acc;
    }
}

// ---------- launch ----------
extern "C" void kernel_launch(void* const* d_in, const int* in_sizes, int n_in,
                              void* d_out, int out_size, void* d_ws, size_t ws_size,
                              hipStream_t stream) {
    const float* x    = (const float*)d_in[0];
    const int*   edge = (const int*)d_in[1];
    const int*   batch= (const int*)d_in[2];
    const float* lam  = (const float*)d_in[3];
    const float* W1   = (const float*)d_in[4];
    const float* b1   = (const float*)d_in[5];
    const float* W2   = (const float*)d_in[6];
    const float* b2   = (const float*)d_in[7];
    const float* Wlin = (const float*)d_in[8];
    const float* blin = (const float*)d_in[9];
    const int E  = in_sizes[1] / 2;
    const int N  = in_sizes[2];
    const int B_ = in_sizes[3];
    const int* row = edge;
    const int* col = edge + E;

    char* ws = (char*)d_ws;
    size_t off = 0;
    auto take = [&](size_t bytes) -> char* {
        char* p = ws + off;
        off = (off + bytes + 255) & ~(size_t)255;
        return p;
    };
    uint16_t* Txb    = (uint16_t*)take((size_t)5 * (N + 1) * 128 * 2);
    int8_t*   Txq    = (int8_t*)take((size_t)5 * (N + 1) * 128);
    uint2*    ew     = (uint2*)take(((size_t)E + 8 * (size_t)N) * 8);
    float*    mS     = (float*)take((size_t)5 * (N + 1) * 4);
    int*      deg    = (int*)take((size_t)N * 4);
    int*      offs   = (int*)take((size_t)(N + 1) * 4);
    float*    dis    = (float*)take((size_t)N * 4);
    float*    diag   = (float*)take((size_t)N * 4);
    uint16_t* Wt1    = (uint16_t*)take((size_t)128 * 640 * 2);
    uint16_t* Wt2    = (uint16_t*)take((size_t)128 * 640 * 2);
    float*    pooled = (float*)take((size_t)B_ * 128 * 4);
    int*      bhist  = (int*)take(257 * 4);
    int*      gbase  = (int*)take(257 * 4);
    int*      gcur   = (int*)take(257 * 4);
    const int nb = (N + 255) / 256;
    int*      psum   = (int*)take((size_t)nb * 4);
    // bout aliased into Txb slot-4 region (written as lhat dst=4 long after last read)
    uint32_t* bout   = (uint32_t*)((char*)Txb + (size_t)4 * (N + 1) * 256);

    hipMemsetAsync(pooled, 0, (size_t)B_ * 128 * 4 + 257 * 4, stream);

    const int nchunks = (E + BINCH - 1) / BINCH;
    const int PREB = nchunks > nb ? nchunks : nb;
    const int lblocks = (N + 3) / 4;
    const int gblocks = (N + BM - 1) / BM;
    const size_t ss = (size_t)(N + 1) * 128;

    // occupancy-derived cooperative grid sizes (cached; host-side pure queries)
    static int s_layerGrid = 0;
    static int s_preMax = 0;
    if (s_layerGrid == 0) {
        int perCU = 0;
        if (hipOccupancyMaxActiveBlocksPerMultiprocessor(&perCU, k_layer, 256, 0) != hipSuccess
            || perCU <= 0) perCU = 2;
        int g = perCU * 256;                  // 256 CUs on MI355X
        if (g > 2048) g = 2048;
        s_layerGrid = g;
        int perCUp = 0;
        if (hipOccupancyMaxActiveBlocksPerMultiprocessor(&perCUp, k_pre, 256, 0) != hipSuccess
            || perCUp <= 0) perCUp = 1;
        s_preMax = perCUp * 256;
    }

    // ---- preprocessing: cooperative if possible, else proven multi-kernel ----
    bool preCoop = (PREB <= s_preMax);
    if (preCoop) {
        int E_ = E, N_ = N, nb_ = nb, nc_ = nchunks;
        const float* x_ = x; const int* row_ = row; const int* col_ = col;
        const int* batch_ = batch; const float* lam_ = lam;
        const float* W1_ = W1; const float* W2_ = W2;
        void* args[] = {
            (void*)&x_, (void*)&row_, (void*)&col_, (void*)&batch_, (void*)&lam_,
            (void*)&W1_, (void*)&Wt1, (void*)&W2_, (void*)&Wt2,
            (void*)&bhist, (void*)&gbase, (void*)&gcur,
            (void*)&bout, (void*)&deg, (void*)&psum,
            (void*)&offs, (void*)&dis, (void*)&diag,
            (void*)&ew, (void*)&mS, (void*)&Txb, (void*)&Txq,
            (void*)&E_, (void*)&N_, (void*)&nb_, (void*)&nc_ };
        hipError_t e = hipLaunchCooperativeKernel((void*)k_pre, dim3(PREB), dim3(256),
                                                  args, 0, stream);
        if (e != hipSuccess) { (void)hipGetLastError(); preCoop = false; }
    }
    if (!preCoop) {
        k_bhist<<<112, 256, 0, stream>>>(row, bhist, E);
        k_bscan<<<1, 256, 0, stream>>>(bhist, gbase, gcur, mS, nb, N);
        k_bin<<<nchunks, 256, 0, stream>>>(row, col, gcur, bout, E);
        k_deg2<<<nb, 256, 0, stream>>>(bout, gbase, deg, psum, N);
        k_offs<<<nb, 256, 0, stream>>>(deg, psum, offs, batch, lam, dis, diag, N, nb);
        k_ew<<<nb, 256, 0, stream>>>(bout, gbase, offs, dis, diag, ew, N);
        k_prepw<<<(2 * 128 * 640) / 256, 256, 0, stream>>>(W1, Wt1, W2, Wt2);
        k_castx<<<(N + 3) / 4, 256, 0, stream>>>(x, Txb, Txq, mS, N);
    }

    // ---- per-layer: cooperative 4-phase lhat if possible, else 4 launches ----
    auto run_layer = [&]() {
        int N_ = N;
        int8_t* Txq_ = Txq; uint16_t* Txb_ = Txb; float* mS_ = mS;
        const int* offs_ = offs; const uint2* ew_ = ew; const float* diag_ = diag;
        void* largs[] = { (void*)&Txq_, (void*)&Txb_, (void*)&mS_,
                          (void*)&offs_, (void*)&ew_, (void*)&diag_, (void*)&N_ };
        hipError_t e = hipLaunchCooperativeKernel((void*)k_layer, dim3(s_layerGrid),
                                                  dim3(256), largs, 0, stream);
        if (e != hipSuccess) {
            (void)hipGetLastError();
            k_lhat<<<lblocks, 256, 0, stream>>>(Txq, Txb, mS, offs, ew, diag, N, 0, 1, 0, 1.f, 0);
            k_lhat<<<lblocks, 256, 0, stream>>>(Txq, Txb, mS, offs, ew, diag, N, 1, 2, 0, 2.f, 1);
            k_lhat<<<lblocks, 256, 0, stream>>>(Txq, Txb, mS, offs, ew, diag, N, 2, 3, 1, 2.f, 1);
            k_lhat<<<lblocks, 256, 0, stream>>>(Txq, Txb, mS, offs, ew, diag, N, 3, 4, 2, 2.f, 1);
        }
    };

    // layer 1
    run_layer();
    k_gemm<<<gblocks, 256, 0, stream>>>(Txb, ss, Wt1, b1,
                                        Txb, Txq, mS,
                                        (float*)nullptr, batch, N, 640);
    // layer 2
    run_layer();
    k_gemm<<<gblocks, 256, 0, stream>>>(Txb, ss, Wt2, b2,
                                        (uint16_t*)nullptr, (int8_t*)nullptr, (float*)nullptr,
                                        pooled, batch, N, 640);

    k_final<<<1, 128, 0, stream>>>(pooled, batch, Wlin, blin, (float*)d_out, N, B_, 10);
}

// Round 5
// 602.845 us; speedup vs baseline: 2.0585x; 2.0585x over previous
//
#include <hip/hip_runtime.h>
#include <stdint.h>

// ---------- helpers ----------
typedef __attribute__((ext_vector_type(8))) short bf16x8;
typedef __attribute__((ext_vector_type(4))) float f32x4;

__device__ __forceinline__ float bf16lo_to_f(uint32_t u) { return __uint_as_float(u << 16); }
__device__ __forceinline__ float bf16hi_to_f(uint32_t u) { return __uint_as_float(u & 0xffff0000u); }
__device__ __forceinline__ uint16_t f_to_bf16(float f) {
    uint32_t u = __float_as_uint(f);
    uint32_t r = u + 0x7fff + ((u >> 16) & 1);   // round-to-nearest-even
    return (uint16_t)(r >> 16);
}

// Layouts:
//  Txb : bf16 [5][N+1][128] -- GEMM A operand mirror (slot-major, 256B rows)
//  Txq : int8 [5][N+1][128] -- gather state (slot-major, 128B rows = 1 cache line)
//  mS  : f32  [5][N+1]      -- per-row quant scale; sentinel row N = 0
//  ew  : uint2 [E + 8N]     -- {col*128 (byte offset into int8 slot), w f32}; pad w=0
//  nh  : uint4 [N]          -- {beg, end, bits(diag), 0} packed node header (1 line)

#define BINCH 4096

// fused: bhist (LDS-aggregated) + prepw + castx -- mutually independent work
__global__ void __launch_bounds__(256) k_pre1(
        const int* __restrict__ row, int* __restrict__ bhist,
        const float* __restrict__ W1, uint16_t* __restrict__ Wt1,
        const float* __restrict__ W2, uint16_t* __restrict__ Wt2,
        const float* __restrict__ x, uint16_t* __restrict__ Txb,
        int8_t* __restrict__ Txq, float* __restrict__ mS,
        int E, int N) {
    __shared__ int sh[256];
    int t = threadIdx.x, b = blockIdx.x;
    int gstride = gridDim.x * 256;
    // bhist
    sh[t] = 0;
    __syncthreads();
    for (int e = b * 256 + t; e < E; e += gstride)
        atomicAdd(&sh[row[e] >> 8], 1);
    __syncthreads();
    if (sh[t]) atomicAdd(&bhist[t], sh[t]);
    // prepw
    for (int i = b * 256 + t; i < 2 * 128 * 640; i += gstride) {
        int ii = i;
        const float* W = W1; uint16_t* Wt = Wt1;
        if (ii >= 128 * 640) { ii -= 128 * 640; W = W2; Wt = Wt2; }
        int o = ii / 640, kk = ii % 640;
        Wt[(size_t)o * 640 + kk] = f_to_bf16(W[(size_t)kk * 128 + o]);
    }
    // castx
    {
        int lane = t & 63;
        int gw = b * 4 + (t >> 6);
        int tw = gridDim.x * 4;
        for (int n = gw; n < N; n += tw) {
            float2 v = ((const float2*)x)[(size_t)n * 64 + lane];
            uint32_t p = (uint32_t)f_to_bf16(v.x) | ((uint32_t)f_to_bf16(v.y) << 16);
            ((uint32_t*)Txb)[(size_t)n * 64 + lane] = p;
            float m = fmaxf(fabsf(v.x), fabsf(v.y));
            for (int o = 1; o < 64; o <<= 1) m = fmaxf(m, __shfl_xor(m, o));
            float inv = m > 0.f ? 127.f / m : 0.f;
            int qx = (int)rintf(v.x * inv), qy = (int)rintf(v.y * inv);
            *(uint16_t*)(Txq + (size_t)n * 128 + 2 * lane) =
                (uint16_t)((qx & 0xff) | ((qy & 0xff) << 8));
            if (lane == 0) mS[n] = m > 0.f ? m * (1.f / 127.f) : 0.f;
        }
    }
}

// scan bucket counts -> gbase/gcur; also zero mS sentinel rows
__global__ void k_bscan(const int* __restrict__ bhist, int* __restrict__ gbase,
                        int* __restrict__ gcur, float* __restrict__ mS, int nbk, int N) {
    __shared__ int sh[256];
    int t = threadIdx.x;
    int v = t < nbk ? bhist[t] : 0;
    sh[t] = v;
    __syncthreads();
    for (int o = 1; o < 256; o <<= 1) {
        int u = (t >= o) ? sh[t - o] : 0;
        __syncthreads();
        sh[t] += u;
        __syncthreads();
    }
    gbase[t] = sh[t] - v;
    gcur[t] = sh[t] - v;
    if (t == 255) gbase[256] = sh[255];
    if (t < 5) mS[(size_t)t * (N + 1) + N] = 0.f;
}

// bin edges into bucket-sorted list; entry = (row&255) | (col<<8)
__global__ void __launch_bounds__(256) k_bin(const int* __restrict__ row,
        const int* __restrict__ col, int* __restrict__ gcur,
        uint32_t* __restrict__ bout, int E) {
    __shared__ uint32_t stage[BINCH];
    __shared__ int hist[256], hscan[256], hcur[256], gofs[256];
    int t = threadIdx.x;
    int e0 = blockIdx.x * BINCH;
    int ecnt = min(BINCH, E - e0);
    hist[t] = 0;
    __syncthreads();
    for (int i = t; i < ecnt; i += 256)
        atomicAdd(&hist[row[e0 + i] >> 8], 1);
    __syncthreads();
    int v = hist[t];
    hscan[t] = v;
    __syncthreads();
    for (int o = 1; o < 256; o <<= 1) {
        int u = (t >= o) ? hscan[t - o] : 0;
        __syncthreads();
        hscan[t] += u;
        __syncthreads();
    }
    hcur[t] = hscan[t] - v;
    __syncthreads();
    for (int i = t; i < ecnt; i += 256) {
        int r = row[e0 + i];
        int p = atomicAdd(&hcur[r >> 8], 1);
        stage[p] = (uint32_t)(r & 255) | ((uint32_t)col[e0 + i] << 8);
    }
    __syncthreads();
    if (v > 0) gofs[t] = atomicAdd(&gcur[t], v);
    __syncthreads();
    for (int i = t; i < ecnt; i += 256) {
        int lo = 0, hi = 255;
        while (lo < hi) { int mid = (lo + hi) >> 1; if (hscan[mid] > i) hi = mid; else lo = mid + 1; }
        int b = lo;
        int local = i - (hscan[b] - hist[b]);
        bout[gofs[b] + local] = stage[i];
    }
}

// per-node degree from bucket lists, fused with padded per-block sum (psum)
__global__ void __launch_bounds__(256) k_deg2(const uint32_t* __restrict__ bout,
        const int* __restrict__ gbase, int* __restrict__ deg,
        int* __restrict__ psum, int N) {
    __shared__ int cnt[256];
    __shared__ int red[256];
    int t = threadIdx.x, b = blockIdx.x;
    cnt[t] = 0;
    __syncthreads();
    int s = gbase[b], epos = gbase[b + 1];
    for (int i = s + t; i < epos; i += 256)
        atomicAdd(&cnt[bout[i] & 255], 1);
    __syncthreads();
    int n = b * 256 + t;
    int d = cnt[t];
    if (n < N) deg[n] = d;
    red[t] = (n < N) ? ((d + 7) & ~7) : 0;
    __syncthreads();
    for (int o = 128; o > 0; o >>= 1) {
        if (t < o) red[t] += red[t + o];
        __syncthreads();
    }
    if (t == 0) psum[b] = red[0];
}

// offs + dis/diag + packed node header nh
__global__ void k_offs(const int* __restrict__ deg, const int* __restrict__ psum,
                       int* __restrict__ offs,
                       const int* __restrict__ batch, const float* __restrict__ lam,
                       float* __restrict__ dis, float* __restrict__ diag,
                       uint4* __restrict__ nh,
                       int N, int nb) {
    __shared__ int pre[256];
    __shared__ int sh[256];
    int t = threadIdx.x, b = blockIdx.x;
    pre[t] = (t < b) ? psum[t] : 0;
    __syncthreads();
    for (int o = 128; o > 0; o >>= 1) {
        if (t < o) pre[t] += pre[t + o];
        __syncthreads();
    }
    int base = pre[0];
    __syncthreads();
    int idx = b * 256 + t;
    int d = idx < N ? deg[idx] : 0;
    int v = (d + 7) & ~7;
    sh[t] = v;
    __syncthreads();
    for (int o = 1; o < 256; o <<= 1) {
        int u = (t >= o) ? sh[t - o] : 0;
        __syncthreads();
        sh[t] += u;
        __syncthreads();
    }
    if (idx < N) {
        int beg = base + sh[t] - v;
        float dgv = 2.f / lam[batch[idx]] - 1.f;
        offs[idx] = beg;
        dis[idx] = d > 0 ? rsqrtf((float)d) : 0.f;
        diag[idx] = dgv;
        nh[idx] = make_uint4((uint32_t)beg, (uint32_t)(base + sh[t]),
                             __float_as_uint(dgv), 0u);
    }
    if (b == nb - 1 && t == 255) offs[N] = base + sh[255];
}

// final scatter: build {col*128, w} edge array (bucket-local) + zero-weight padding
__global__ void __launch_bounds__(256) k_ew(const uint32_t* __restrict__ bout,
        const int* __restrict__ gbase, const int* __restrict__ offs,
        const float* __restrict__ dis, const float* __restrict__ diag,
        uint2* __restrict__ ew, int N) {
    __shared__ int cur[256];
    __shared__ float srw[256];        // per-local-row  -dis[r]*(diag[r]+1)
    int t = threadIdx.x, b = blockIdx.x;
    int n = b * 256 + t;
    int o0 = n < N ? offs[n] : 0;
    cur[t] = o0;
    srw[t] = (n < N) ? (-dis[n] * (diag[n] + 1.0f)) : 0.f;
    __syncthreads();
    int s = gbase[b], epos = gbase[b + 1];
    for (int i = s + t; i < epos; i += 256) {
        uint32_t v = bout[i];
        int r = (int)(v & 255u);
        int c = (int)(v >> 8);
        int p = atomicAdd(&cur[r], 1);
        float w = srw[r] * dis[c];
        ew[p] = make_uint2((uint32_t)c << 7, __float_as_uint(w));
    }
    __syncthreads();
    if (n < N) {
        int e = cur[t];
        int pe = o0 + ((e - o0 + 7) & ~7);
        uint2 pad = make_uint2((uint32_t)N << 7, 0u);
        for (int p = e; p < pe; p++) ew[p] = pad;
    }
}

// =========================================================================
// k_lhat2: TWO nodes per wave, interleaved edge loops (2 independent memory
// chains in flight -> ILP latency hiding; half the blocks of round-2).
// Numerics identical to round-2 k_lhat.
// =========================================================================
__global__ void __launch_bounds__(256) k_lhat2(
        int8_t* __restrict__ Txq, uint16_t* __restrict__ Txb,
        float* __restrict__ mS,
        const uint4* __restrict__ nh, const uint2* __restrict__ ew,
        int N,
        int src, int dst, int prev, float alpha, int use_prev) {
    int wid = (blockIdx.x * blockDim.x + threadIdx.x) >> 6;
    int lane = threadIdx.x & 63;
    int n0 = wid * 2;
    if (n0 >= N) return;
    int n1 = n0 + 1;
    bool has1 = n1 < N;
    int h = lane >> 5, g = lane & 31;
    size_t sq = (size_t)(N + 1) * 128;
    const int8_t* srcq = Txq + (size_t)src * sq;
    const float* msrc = mS + (size_t)src * (N + 1);
    uint32_t lo4 = (uint32_t)g * 4;
    const uint2* ewh = ew + h;

    uint4 h0 = nh[n0];
    uint4 h1 = has1 ? nh[n1] : make_uint4(0, 0, 0, 0);
    int e0 = (int)h0.x, end0 = (int)h0.y;
    int e1 = (int)h1.x, end1 = (int)h1.y;
    float dg0 = __uint_as_float(h0.z), dg1 = __uint_as_float(h1.z);

    float A00 = 0.f, A01 = 0.f, A02 = 0.f, A03 = 0.f;
    float A10 = 0.f, A11 = 0.f, A12 = 0.f, A13 = 0.f;

    bool a0 = e0 < end0, a1 = e1 < end1;
    uint2 p0[4], p1[4];
    if (a0) {
#pragma unroll
        for (int p = 0; p < 4; p++) p0[p] = ewh[e0 + 2 * p];
    }
    if (a1) {
#pragma unroll
        for (int p = 0; p < 4; p++) p1[p] = ewh[e1 + 2 * p];
    }
    while (a0 | a1) {
        uint32_t q0[4], q1[4];
        float m0[4], w0[4], m1[4], w1[4];
        if (a0) {
#pragma unroll
            for (int p = 0; p < 4; p++) {
                uint32_t co = p0[p].x;
                w0[p] = __uint_as_float(p0[p].y);
                q0[p] = *(const uint32_t*)(srcq + co + lo4);
                m0[p] = *(const float*)((const char*)msrc + (co >> 5));
            }
        }
        if (a1) {
#pragma unroll
            for (int p = 0; p < 4; p++) {
                uint32_t co = p1[p].x;
                w1[p] = __uint_as_float(p1[p].y);
                q1[p] = *(const uint32_t*)(srcq + co + lo4);
                m1[p] = *(const float*)((const char*)msrc + (co >> 5));
            }
        }
        int e0n = e0 + 8, e1n = e1 + 8;
        bool a0n = a0 && (e0n < end0);
        bool a1n = a1 && (e1n < end1);
        uint2 p0n[4], p1n[4];
        if (a0n) {
#pragma unroll
            for (int p = 0; p < 4; p++) p0n[p] = ewh[e0n + 2 * p];
        }
        if (a1n) {
#pragma unroll
            for (int p = 0; p < 4; p++) p1n[p] = ewh[e1n + 2 * p];
        }
        if (a0) {
#pragma unroll
            for (int p = 0; p < 4; p++) {
                float f = w0[p] * m0[p];
                A00 = fmaf(f, (float)(int)(int8_t)(q0[p] & 0xff), A00);
                A01 = fmaf(f, (float)(int)(int8_t)((q0[p] >> 8) & 0xff), A01);
                A02 = fmaf(f, (float)(int)(int8_t)((q0[p] >> 16) & 0xff), A02);
                A03 = fmaf(f, (float)(int)(int8_t)(q0[p] >> 24), A03);
            }
        }
        if (a1) {
#pragma unroll
            for (int p = 0; p < 4; p++) {
                float f = w1[p] * m1[p];
                A10 = fmaf(f, (float)(int)(int8_t)(q1[p] & 0xff), A10);
                A11 = fmaf(f, (float)(int)(int8_t)((q1[p] >> 8) & 0xff), A11);
                A12 = fmaf(f, (float)(int)(int8_t)((q1[p] >> 16) & 0xff), A12);
                A13 = fmaf(f, (float)(int)(int8_t)(q1[p] >> 24), A13);
            }
        }
        e0 = e0n; e1 = e1n;
        if (a0n) {
#pragma unroll
            for (int p = 0; p < 4; p++) p0[p] = p0n[p];
        }
        if (a1n) {
#pragma unroll
            for (int p = 0; p < 4; p++) p1[p] = p1n[p];
        }
        a0 = a0n; a1 = a1n;
    }

    auto epi = [&](int n, float f0a, float f1a, float f2a, float f3a, float dgn) {
        float b0 = f0a + __shfl_xor(f0a, 32);
        float b1 = f1a + __shfl_xor(f1a, 32);
        float b2 = f2a + __shfl_xor(f2a, 32);
        float b3 = f3a + __shfl_xor(f3a, 32);
        uint32_t rq = (uint32_t)n * 128 + lo4;
        uint32_t qs = *(const uint32_t*)(srcq + rq);
        float ssc = msrc[n] * dgn;
        b0 = fmaf(ssc, (float)(int)(int8_t)(qs & 0xff), b0);
        b1 = fmaf(ssc, (float)(int)(int8_t)((qs >> 8) & 0xff), b1);
        b2 = fmaf(ssc, (float)(int)(int8_t)((qs >> 16) & 0xff), b2);
        b3 = fmaf(ssc, (float)(int)(int8_t)(qs >> 24), b3);
        float f0 = alpha * b0, f1 = alpha * b1, f2 = alpha * b2, f3 = alpha * b3;
        if (use_prev) {
            uint32_t qp = *(const uint32_t*)(Txq + (size_t)prev * sq + rq);
            float sp = mS[(size_t)prev * (N + 1) + n];
            f0 = fmaf(-sp, (float)(int)(int8_t)(qp & 0xff), f0);
            f1 = fmaf(-sp, (float)(int)(int8_t)((qp >> 8) & 0xff), f1);
            f2 = fmaf(-sp, (float)(int)(int8_t)((qp >> 16) & 0xff), f2);
            f3 = fmaf(-sp, (float)(int)(int8_t)(qp >> 24), f3);
        }
        if (h == 0) {
            uint2 pk;
            pk.x = (uint32_t)f_to_bf16(f0) | ((uint32_t)f_to_bf16(f1) << 16);
            pk.y = (uint32_t)f_to_bf16(f2) | ((uint32_t)f_to_bf16(f3) << 16);
            *(uint2*)(Txb + (size_t)dst * (size_t)(N + 1) * 128 + (size_t)n * 128 + g * 4) = pk;
        }
        float m = fmaxf(fmaxf(fabsf(f0), fabsf(f1)), fmaxf(fabsf(f2), fabsf(f3)));
#pragma unroll
        for (int o = 1; o < 32; o <<= 1) m = fmaxf(m, __shfl_xor(m, o));
        float inv = m > 0.f ? 127.f / m : 0.f;
        if (h == 0) {
            int q0v = (int)rintf(f0 * inv), q1v = (int)rintf(f1 * inv);
            int q2v = (int)rintf(f2 * inv), q3v = (int)rintf(f3 * inv);
            uint32_t pkq = (uint32_t)(q0v & 0xff) | ((uint32_t)(q1v & 0xff) << 8) |
                           ((uint32_t)(q2v & 0xff) << 16) | ((uint32_t)(q3v & 0xff) << 24);
            *(uint32_t*)(Txq + (size_t)dst * sq + rq) = pkq;
        }
        if (lane == 0) mS[(size_t)dst * (N + 1) + n] = m * (1.f / 127.f);
    };
    epi(n0, A00, A01, A02, A03, dg0);
    if (has1) epi(n1, A10, A11, A12, A13, dg1);
}

// ---------- GEMM: relu(A[M,640] @ Wt^T + bias), bf16 MFMA, BM=128 tile ----------
#define BM 128
#define BK 64
#define LDT 72
#define LDC 132

__global__ void __launch_bounds__(256) k_gemm(
        const uint16_t* __restrict__ A, size_t sstride,
        const uint16_t* __restrict__ Bt,
        const float* __restrict__ bias,
        uint16_t* __restrict__ out2b,
        int8_t* __restrict__ out2q,
        float* __restrict__ msOut,
        float* __restrict__ pooled,
        const int* __restrict__ batch,
        int M, int Kdim) {
    __shared__ uint16_t smem[BM * LDT + 128 * LDT];
    uint16_t* As = smem;
    uint16_t* Bs = smem + BM * LDT;
    uint16_t* Ct = smem;
    int t = threadIdx.x;
    int w = t >> 6, lane = t & 63;
    int row0 = blockIdx.x * BM;
    int mrow = (w >> 1) * 64, ncol = (w & 1) * 64;

    int ar[4], akc[4];
#pragma unroll
    for (int rep = 0; rep < 4; rep++) {
        int d = rep * 256 + t;
        ar[rep] = d >> 3; akc[rep] = d & 7;
    }

    f32x4 acc[4][4];
#pragma unroll
    for (int i = 0; i < 4; i++)
#pragma unroll
        for (int j = 0; j < 4; j++) acc[i][j] = (f32x4){0.f, 0.f, 0.f, 0.f};

    bf16x8 pa[4], pb[4];
#pragma unroll
    for (int rep = 0; rep < 4; rep++) {
        int grow = row0 + ar[rep];
        int kk = akc[rep] * 8;
        bf16x8 va = {0, 0, 0, 0, 0, 0, 0, 0};
        if (grow < M)
            va = *(const bf16x8*)(A + (size_t)(kk >> 7) * sstride + (size_t)grow * 128 + (kk & 127));
        pa[rep] = va;
        pb[rep] = *(const bf16x8*)(Bt + (size_t)ar[rep] * Kdim + kk);
    }

    for (int k0 = 0; k0 < Kdim; k0 += BK) {
#pragma unroll
        for (int rep = 0; rep < 4; rep++) {
            *(bf16x8*)(&As[ar[rep] * LDT + akc[rep] * 8]) = pa[rep];
            *(bf16x8*)(&Bs[ar[rep] * LDT + akc[rep] * 8]) = pb[rep];
        }
        __syncthreads();
        int kn = k0 + BK;
        if (kn < Kdim) {
#pragma unroll
            for (int rep = 0; rep < 4; rep++) {
                int grow = row0 + ar[rep];
                int kk = kn + akc[rep] * 8;
                bf16x8 va = {0, 0, 0, 0, 0, 0, 0, 0};
                if (grow < M)
                    va = *(const bf16x8*)(A + (size_t)(kk >> 7) * sstride + (size_t)grow * 128 + (kk & 127));
                pa[rep] = va;
                pb[rep] = *(const bf16x8*)(Bt + (size_t)ar[rep] * Kdim + kk);
            }
        }
#pragma unroll
        for (int ks = 0; ks < BK; ks += 32) {
            bf16x8 af[4], bfr[4];
#pragma unroll
            for (int i = 0; i < 4; i++) {
                int r = mrow + i * 16 + (lane & 15);
                af[i] = *(const bf16x8*)(&As[r * LDT + ks + (lane >> 4) * 8]);
            }
#pragma unroll
            for (int j = 0; j < 4; j++) {
                int c = ncol + j * 16 + (lane & 15);
                bfr[j] = *(const bf16x8*)(&Bs[c * LDT + ks + (lane >> 4) * 8]);
            }
#pragma unroll
            for (int i = 0; i < 4; i++)
#pragma unroll
                for (int j = 0; j < 4; j++)
                    acc[i][j] = __builtin_amdgcn_mfma_f32_16x16x32_bf16(af[i], bfr[j], acc[i][j], 0, 0, 0);
        }
        __syncthreads();
    }

#pragma unroll
    for (int j = 0; j < 4; j++) {
        int c = ncol + j * 16 + (lane & 15);
        float bv = bias[c];
#pragma unroll
        for (int i = 0; i < 4; i++) {
            int rloc = mrow + i * 16 + (lane >> 4) * 4;
#pragma unroll
            for (int r = 0; r < 4; r++) {
                float v = acc[i][j][r] + bv;
                v = v > 0.f ? v : 0.f;
                Ct[(rloc + r) * LDC + c] = f_to_bf16(v);
            }
        }
    }
    __syncthreads();

    if (out2b) {
#pragma unroll
        for (int rep = 0; rep < 8; rep++) {
            int d = rep * 256 + t;
            int r = d >> 4, c8 = (d & 15) * 8;
            int grow = row0 + r;
            if (grow < M) {
                bf16x8 v = *(const bf16x8*)(&Ct[r * LDC + c8]);
                *(bf16x8*)(out2b + (size_t)grow * 128 + c8) = v;
            }
        }
    }
    if (out2q) {
        int r = t >> 1, half = t & 1;
        int grow = row0 + r;
        float vmax = 0.f;
        for (int j = 0; j < 32; j++) {
            uint32_t u = *(const uint32_t*)(&Ct[r * LDC + half * 64 + j * 2]);
            vmax = fmaxf(vmax, fmaxf(fabsf(bf16lo_to_f(u)), fabsf(bf16hi_to_f(u))));
        }
        vmax = fmaxf(vmax, __shfl_xor(vmax, 1));
        if (grow < M) {
            float inv = vmax > 0.f ? 127.f / vmax : 0.f;
            for (int j0 = 0; j0 < 16; j0++) {
                uint32_t u0 = *(const uint32_t*)(&Ct[r * LDC + half * 64 + j0 * 4]);
                uint32_t u1 = *(const uint32_t*)(&Ct[r * LDC + half * 64 + j0 * 4 + 2]);
                int q0 = (int)rintf(bf16lo_to_f(u0) * inv);
                int q1 = (int)rintf(bf16hi_to_f(u0) * inv);
                int q2 = (int)rintf(bf16lo_to_f(u1) * inv);
                int q3 = (int)rintf(bf16hi_to_f(u1) * inv);
                uint32_t pk = (uint32_t)(q0 & 0xff) | ((uint32_t)(q1 & 0xff) << 8) |
                              ((uint32_t)(q2 & 0xff) << 16) | ((uint32_t)(q3 & 0xff) << 24);
                *(uint32_t*)(out2q + (size_t)grow * 128 + half * 64 + j0 * 4) = pk;
            }
            if (half == 0) msOut[grow] = vmax * (1.f / 127.f);
        }
    }
    if (pooled) {
        int f = t & 127, r0 = (t >> 7) * 64;
        float accp = 0.f;
        int curb = -1;
        for (int r = r0; r < r0 + 64; ++r) {
            int grow = row0 + r;
            if (grow >= M) break;
            int b = batch[grow];
            if (b != curb) {
                if (curb >= 0) atomicAdd(&pooled[curb * 128 + f], accp);
                accp = 0.f; curb = b;
            }
            accp += __uint_as_float(((uint32_t)Ct[r * LDC + f]) << 16);
        }
        if (curb >= 0) atomicAdd(&pooled[curb * 128 + f], accp);
    }
}

// ---------- final linear ----------
__global__ void k_final(const float* __restrict__ pooled, const int* __restrict__ batch,
                        const float* __restrict__ Wlin, const float* __restrict__ blin,
                        float* __restrict__ out, int N, int B_, int C_) {
    __shared__ int cnt[64];
    int t = threadIdx.x;
    if (t < B_) {
        auto lb = [&](int v) {
            int lo = 0, hi = N;
            while (lo < hi) {
                int mid = (lo + hi) >> 1;
                if (batch[mid] < v) lo = mid + 1; else hi = mid;
            }
            return lo;
        };
        cnt[t] = lb(t + 1) - lb(t);
    }
    __syncthreads();
    if (t < B_ * C_) {
        int b = t / C_, c = t % C_;
        float inv = 1.f / fmaxf((float)cnt[b], 1.f);
        float acc = blin[c];
        for (int f = 0; f < 128; ++f) acc += pooled[b * 128 + f] * inv * Wlin[f * C_ + c];
        out[t] = acc;
    }
}

// ---------- launch ----------
extern "C" void kernel_launch(void* const* d_in, const int* in_sizes, int n_in,
                              void* d_out, int out_size, void* d_ws, size_t ws_size,
                              hipStream_t stream) {
    const float* x    = (const float*)d_in[0];
    const int*   edge = (const int*)d_in[1];
    const int*   batch= (const int*)d_in[2];
    const float* lam  = (const float*)d_in[3];
    const float* W1   = (const float*)d_in[4];
    const float* b1   = (const float*)d_in[5];
    const float* W2   = (const float*)d_in[6];
    const float* b2   = (const float*)d_in[7];
    const float* Wlin = (const float*)d_in[8];
    const float* blin = (const float*)d_in[9];
    const int E  = in_sizes[1] / 2;
    const int N  = in_sizes[2];
    const int B_ = in_sizes[3];
    const int* row = edge;
    const int* col = edge + E;

    char* ws = (char*)d_ws;
    size_t off = 0;
    auto take = [&](size_t bytes) -> char* {
        char* p = ws + off;
        off = (off + bytes + 255) & ~(size_t)255;
        return p;
    };
    uint16_t* Txb    = (uint16_t*)take((size_t)5 * (N + 1) * 128 * 2);
    int8_t*   Txq    = (int8_t*)take((size_t)5 * (N + 1) * 128);
    uint2*    ew     = (uint2*)take(((size_t)E + 8 * (size_t)N) * 8);
    float*    mS     = (float*)take((size_t)5 * (N + 1) * 4);
    int*      deg    = (int*)take((size_t)N * 4);
    int*      offs   = (int*)take((size_t)(N + 1) * 4);
    float*    dis    = (float*)take((size_t)N * 4);
    float*    diag   = (float*)take((size_t)N * 4);
    uint4*    nh     = (uint4*)take((size_t)N * 16);
    uint16_t* Wt1    = (uint16_t*)take((size_t)128 * 640 * 2);
    uint16_t* Wt2    = (uint16_t*)take((size_t)128 * 640 * 2);
    float*    pooled = (float*)take((size_t)B_ * 128 * 4);
    int*      bhist  = (int*)take(257 * 4);                  // contiguous after pooled
    int*      gbase  = (int*)take(257 * 4);
    int*      gcur   = (int*)take(257 * 4);
    const int nb = (N + 255) / 256;
    int*      psum   = (int*)take((size_t)nb * 4);
    // bout aliased into Txb slot-4 region (written as lhat dst=4 long after last read)
    uint32_t* bout   = (uint32_t*)((char*)Txb + (size_t)4 * (N + 1) * 256);

    // one fill covers pooled (B_*512 bytes, 256-multiple) + bhist
    hipMemsetAsync(pooled, 0, (size_t)B_ * 128 * 4 + 257 * 4, stream);

    const int nchunks = (E + BINCH - 1) / BINCH;

    k_pre1<<<1024, 256, 0, stream>>>(row, bhist, W1, Wt1, W2, Wt2,
                                     x, Txb, Txq, mS, E, N);
    k_bscan<<<1, 256, 0, stream>>>(bhist, gbase, gcur, mS, nb, N);
    k_bin<<<nchunks, 256, 0, stream>>>(row, col, gcur, bout, E);
    k_deg2<<<nb, 256, 0, stream>>>(bout, gbase, deg, psum, N);
    k_offs<<<nb, 256, 0, stream>>>(deg, psum, offs, batch, lam, dis, diag, nh, N, nb);
    k_ew<<<nb, 256, 0, stream>>>(bout, gbase, offs, dis, diag, ew, N);

    const int l2blocks = (N + 7) / 8;          // 2 nodes/wave, 4 waves/block
    const int gblocks = (N + BM - 1) / BM;
    const size_t ss = (size_t)(N + 1) * 128;

    // layer 1
    k_lhat2<<<l2blocks, 256, 0, stream>>>(Txq, Txb, mS, nh, ew, N, 0, 1, 0, 1.f, 0);
    k_lhat2<<<l2blocks, 256, 0, stream>>>(Txq, Txb, mS, nh, ew, N, 1, 2, 0, 2.f, 1);
    k_lhat2<<<l2blocks, 256, 0, stream>>>(Txq, Txb, mS, nh, ew, N, 2, 3, 1, 2.f, 1);
    k_lhat2<<<l2blocks, 256, 0, stream>>>(Txq, Txb, mS, nh, ew, N, 3, 4, 2, 2.f, 1);
    k_gemm<<<gblocks, 256, 0, stream>>>(Txb, ss, Wt1, b1,
                                        Txb, Txq, mS,
                                        (float*)nullptr, batch, N, 640);
    // layer 2
    k_lhat2<<<l2blocks, 256, 0, stream>>>(Txq, Txb, mS, nh, ew, N, 0, 1, 0, 1.f, 0);
    k_lhat2<<<l2blocks, 256, 0, stream>>>(Txq, Txb, mS, nh, ew, N, 1, 2, 0, 2.f, 1);
    k_lhat2<<<l2blocks, 256, 0, stream>>>(Txq, Txb, mS, nh, ew, N, 2, 3, 1, 2.f, 1);
    k_lhat2<<<l2blocks, 256, 0, stream>>>(Txq, Txb, mS, nh, ew, N, 3, 4, 2, 2.f, 1);
    k_gemm<<<gblocks, 256, 0, stream>>>(Txb, ss, Wt2, b2,
                                        (uint16_t*)nullptr, (int8_t*)nullptr, (float*)nullptr,
                                        pooled, batch, N, 640);

    k_final<<<1, 128, 0, stream>>>(pooled, batch, Wlin, blin, (float*)d_out, N, B_, 10);
}

// Round 6
// 469.958 us; speedup vs baseline: 2.6406x; 1.2828x over previous
//
#include <hip/hip_runtime.h>
#include <stdint.h>

// ---------- helpers ----------
typedef __attribute__((ext_vector_type(8))) short bf16x8;
typedef __attribute__((ext_vector_type(4))) float f32x4;

__device__ __forceinline__ float bf16lo_to_f(uint32_t u) { return __uint_as_float(u << 16); }
__device__ __forceinline__ float bf16hi_to_f(uint32_t u) { return __uint_as_float(u & 0xffff0000u); }
__device__ __forceinline__ uint16_t f_to_bf16(float f) {
    uint32_t u = __float_as_uint(f);
    uint32_t r = u + 0x7fff + ((u >> 16) & 1);   // round-to-nearest-even
    return (uint16_t)(r >> 16);
}

// Layouts:
//  Txb : bf16 [5][N+1][128] -- Chebyshev state, slot-major, 256B rows; row N = 0
//  ew  : u32 [E + 8N] -- {col u16 | bf16(w) << 16}; packet of 8 edges stored as
//        [h0e0 h0e1 h0e2 h0e3 | h1e0 h1e1 h1e2 h1e3]; half-wave h reads ONE uint4.
//  nh  : uint4 [N] -- {beg, end, bits(diag), 0} packed node header (1 line)

#define BINCH 4096

__global__ void __launch_bounds__(256) k_bhist(const int* __restrict__ row,
                                               int* __restrict__ bhist, int E) {
    __shared__ int sh[256];
    int t = threadIdx.x;
    sh[t] = 0;
    __syncthreads();
    int stride = gridDim.x * blockDim.x;
    for (int e = blockIdx.x * blockDim.x + t; e < E; e += stride)
        atomicAdd(&sh[row[e] >> 8], 1);
    __syncthreads();
    if (sh[t]) atomicAdd(&bhist[t], sh[t]);
}

// scan bucket counts -> gbase/gcur
__global__ void k_bscan(const int* __restrict__ bhist, int* __restrict__ gbase,
                        int* __restrict__ gcur, int nbk) {
    __shared__ int sh[256];
    int t = threadIdx.x;
    int v = t < nbk ? bhist[t] : 0;
    sh[t] = v;
    __syncthreads();
    for (int o = 1; o < 256; o <<= 1) {
        int u = (t >= o) ? sh[t - o] : 0;
        __syncthreads();
        sh[t] += u;
        __syncthreads();
    }
    gbase[t] = sh[t] - v;
    gcur[t] = sh[t] - v;
    if (t == 255) gbase[256] = sh[255];
}

// bin edges into bucket-sorted list; entry = (row&255) | (col<<8)
__global__ void __launch_bounds__(256) k_bin(const int* __restrict__ row,
        const int* __restrict__ col, int* __restrict__ gcur,
        uint32_t* __restrict__ bout, int E) {
    __shared__ uint32_t stage[BINCH];
    __shared__ int hist[256], hscan[256], hcur[256], gofs[256];
    int t = threadIdx.x;
    int e0 = blockIdx.x * BINCH;
    int ecnt = min(BINCH, E - e0);
    hist[t] = 0;
    __syncthreads();
    for (int i = t; i < ecnt; i += 256)
        atomicAdd(&hist[row[e0 + i] >> 8], 1);
    __syncthreads();
    int v = hist[t];
    hscan[t] = v;
    __syncthreads();
    for (int o = 1; o < 256; o <<= 1) {
        int u = (t >= o) ? hscan[t - o] : 0;
        __syncthreads();
        hscan[t] += u;
        __syncthreads();
    }
    hcur[t] = hscan[t] - v;
    __syncthreads();
    for (int i = t; i < ecnt; i += 256) {
        int r = row[e0 + i];
        int p = atomicAdd(&hcur[r >> 8], 1);
        stage[p] = (uint32_t)(r & 255) | ((uint32_t)col[e0 + i] << 8);
    }
    __syncthreads();
    if (v > 0) gofs[t] = atomicAdd(&gcur[t], v);
    __syncthreads();
    for (int i = t; i < ecnt; i += 256) {
        int lo = 0, hi = 255;
        while (lo < hi) { int mid = (lo + hi) >> 1; if (hscan[mid] > i) hi = mid; else lo = mid + 1; }
        int b = lo;
        int local = i - (hscan[b] - hist[b]);
        bout[gofs[b] + local] = stage[i];
    }
}

// per-node degree from bucket lists, fused with padded per-block sum (psum)
__global__ void __launch_bounds__(256) k_deg2(const uint32_t* __restrict__ bout,
        const int* __restrict__ gbase, int* __restrict__ deg,
        int* __restrict__ psum, int N) {
    __shared__ int cnt[256];
    __shared__ int red[256];
    int t = threadIdx.x, b = blockIdx.x;
    cnt[t] = 0;
    __syncthreads();
    int s = gbase[b], epos = gbase[b + 1];
    for (int i = s + t; i < epos; i += 256)
        atomicAdd(&cnt[bout[i] & 255], 1);
    __syncthreads();
    int n = b * 256 + t;
    int d = cnt[t];
    if (n < N) deg[n] = d;
    red[t] = (n < N) ? ((d + 7) & ~7) : 0;
    __syncthreads();
    for (int o = 128; o > 0; o >>= 1) {
        if (t < o) red[t] += red[t + o];
        __syncthreads();
    }
    if (t == 0) psum[b] = red[0];
}

// offs + dis/diag + packed node header nh
__global__ void k_offs(const int* __restrict__ deg, const int* __restrict__ psum,
                       int* __restrict__ offs,
                       const int* __restrict__ batch, const float* __restrict__ lam,
                       float* __restrict__ dis, float* __restrict__ diag,
                       uint4* __restrict__ nh,
                       int N, int nb) {
    __shared__ int pre[256];
    __shared__ int sh[256];
    int t = threadIdx.x, b = blockIdx.x;
    pre[t] = (t < b) ? psum[t] : 0;
    __syncthreads();
    for (int o = 128; o > 0; o >>= 1) {
        if (t < o) pre[t] += pre[t + o];
        __syncthreads();
    }
    int base = pre[0];
    __syncthreads();
    int idx = b * 256 + t;
    int d = idx < N ? deg[idx] : 0;
    int v = (d + 7) & ~7;
    sh[t] = v;
    __syncthreads();
    for (int o = 1; o < 256; o <<= 1) {
        int u = (t >= o) ? sh[t - o] : 0;
        __syncthreads();
        sh[t] += u;
        __syncthreads();
    }
    if (idx < N) {
        int beg = base + sh[t] - v;
        float dgv = 2.f / lam[batch[idx]] - 1.f;
        offs[idx] = beg;
        dis[idx] = d > 0 ? rsqrtf((float)d) : 0.f;
        diag[idx] = dgv;
        nh[idx] = make_uint4((uint32_t)beg, (uint32_t)(base + sh[t] - v + v),
                             __float_as_uint(dgv), 0u);
    }
    if (b == nb - 1 && t == 255) offs[N] = base + sh[255];
}

// final scatter: packed 4B edge entries {col u16 | bf16(w)<<16} in half-split
// packet order: idx i within node -> pos = (i&~7) + ((i&1)<<2) + ((i>>1)&3)
__global__ void __launch_bounds__(256) k_ew(const uint32_t* __restrict__ bout,
        const int* __restrict__ gbase, const int* __restrict__ offs,
        const float* __restrict__ dis, const float* __restrict__ diag,
        uint32_t* __restrict__ ew, int N) {
    __shared__ int cur[256];
    __shared__ int bs0[256];
    __shared__ float srw[256];        // per-local-row  -dis[r]*(diag[r]+1)
    int t = threadIdx.x, b = blockIdx.x;
    int n = b * 256 + t;
    int o0 = n < N ? offs[n] : 0;
    cur[t] = 0;
    bs0[t] = o0;
    srw[t] = (n < N) ? (-dis[n] * (diag[n] + 1.0f)) : 0.f;
    __syncthreads();
    int s = gbase[b], epos = gbase[b + 1];
    for (int i = s + t; i < epos; i += 256) {
        uint32_t v = bout[i];
        int r = (int)(v & 255u);
        int c = (int)(v >> 8);
        int idx = atomicAdd(&cur[r], 1);
        float w = srw[r] * dis[c];
        int pos = bs0[r] + (idx & ~7) + ((idx & 1) << 2) + ((idx >> 1) & 3);
        ew[pos] = (uint32_t)c | ((uint32_t)f_to_bf16(w) << 16);
    }
    __syncthreads();
    if (n < N) {
        int cnt = cur[t];
        int pe = (cnt + 7) & ~7;
        for (int i = cnt; i < pe; i++) {
            int pos = o0 + (i & ~7) + ((i & 1) << 2) + ((i >> 1) & 3);
            ew[pos] = (uint32_t)N;            // w = 0 (bf16 zero in high bits)
        }
    }
}

// W1,W2 [5][128][128] fp32 -> Wt bf16 [128 out][640 kk]; fused pair
__global__ void k_prepw(const float* __restrict__ W1, uint16_t* __restrict__ Wt1,
                        const float* __restrict__ W2, uint16_t* __restrict__ Wt2) {
    int i = blockIdx.x * blockDim.x + threadIdx.x;
    const float* W = W1; uint16_t* Wt = Wt1;
    if (i >= 128 * 640) { i -= 128 * 640; W = W2; Wt = Wt2; }
    int o = i / 640, kk = i % 640;
    Wt[(size_t)o * 640 + kk] = f_to_bf16(W[(size_t)kk * 128 + o]);
}

// x fp32 [N][128] -> Txb slot 0 bf16; wave n==N zeroes the 5 sentinel rows
__global__ void __launch_bounds__(256) k_castx(const float* __restrict__ x,
        uint16_t* __restrict__ Txb, int N) {
    int n = (blockIdx.x * blockDim.x + threadIdx.x) >> 6;
    int lane = threadIdx.x & 63;
    if (n > N) return;
    size_t ss32 = (size_t)(N + 1) * 64;          // u32 per slot
    if (n == N) {
#pragma unroll
        for (int s = 0; s < 5; s++)
            ((uint32_t*)Txb)[s * ss32 + (size_t)N * 64 + lane] = 0u;
        return;
    }
    float2 v = ((const float2*)x)[(size_t)n * 64 + lane];
    uint32_t p = (uint32_t)f_to_bf16(v.x) | ((uint32_t)f_to_bf16(v.y) << 16);
    ((uint32_t*)Txb)[(size_t)n * 64 + lane] = p;
}

// =========================================================================
// k_lhat: dst = alpha*(sum_e w_e*src[col] + diag*src[n]) - (use_prev?prev:0)
// bf16 state; 2 edges per wave-step (half-waves); 5 vector loads per 8-edge
// packet: 1 uint4 (4 packed edge descriptors) + 4 uint2 q-loads.
// =========================================================================
__global__ void __launch_bounds__(256) k_lhat(uint16_t* __restrict__ Txb,
        const uint4* __restrict__ nh, const uint32_t* __restrict__ ew,
        int N,
        int src, int dst, int prev, float alpha, int use_prev) {
    int n = (blockIdx.x * blockDim.x + threadIdx.x) >> 6;
    int lane = threadIdx.x & 63;
    if (n >= N) return;
    int h = lane >> 5, g = lane & 31;
    size_t sb = (size_t)(N + 1) * 256;           // bytes per slot
    const uint8_t* srcs = (const uint8_t*)Txb + (size_t)src * sb;
    uint32_t g8 = (uint32_t)g * 8;
    uint4 hh = nh[n];
    int e = (int)hh.x, end = (int)hh.y;
    float dgn = __uint_as_float(hh.z);
    float a0 = 0.f, a1 = 0.f, a2 = 0.f, a3 = 0.f;
    if (e < end) {
        const uint4* ep = (const uint4*)(ew + e + h * 4);  // half h's lane in packet 0
        int npk = (end - e) >> 3;
        uint4 c = ep[0];
        int pk = 0;
        while (true) {
            bool more = (pk + 1) < npk;
            uint4 cn;
            if (more) cn = ep[(pk + 1) * 2];     // 8 u32 per packet = 2 uint4
#pragma unroll
            for (int u = 0; u < 4; u++) {
                uint32_t cw = (&c.x)[u];
                uint32_t addr = (cw & 0xffffu) << 8;
                float w = __uint_as_float(cw & 0xffff0000u);
                uint2 q = *(const uint2*)(srcs + addr + g8);
                a0 = fmaf(w, bf16lo_to_f(q.x), a0);
                a1 = fmaf(w, bf16hi_to_f(q.x), a1);
                a2 = fmaf(w, bf16lo_to_f(q.y), a2);
                a3 = fmaf(w, bf16hi_to_f(q.y), a3);
            }
            if (!more) break;
            c = cn;
            pk++;
        }
    }
    // combine the two edge-halves
    a0 += __shfl_xor(a0, 32);
    a1 += __shfl_xor(a1, 32);
    a2 += __shfl_xor(a2, 32);
    a3 += __shfl_xor(a3, 32);
    if (h == 0) {
        size_t ro = (size_t)n * 256 + g8;
        uint2 qs = *(const uint2*)(srcs + ro);
        a0 = fmaf(dgn, bf16lo_to_f(qs.x), a0);
        a1 = fmaf(dgn, bf16hi_to_f(qs.x), a1);
        a2 = fmaf(dgn, bf16lo_to_f(qs.y), a2);
        a3 = fmaf(dgn, bf16hi_to_f(qs.y), a3);
        float f0 = alpha * a0, f1 = alpha * a1, f2 = alpha * a2, f3 = alpha * a3;
        if (use_prev) {
            uint2 qp = *(const uint2*)((const uint8_t*)Txb + (size_t)prev * sb + ro);
            f0 -= bf16lo_to_f(qp.x);
            f1 -= bf16hi_to_f(qp.x);
            f2 -= bf16lo_to_f(qp.y);
            f3 -= bf16hi_to_f(qp.y);
        }
        uint2 pk2;
        pk2.x = (uint32_t)f_to_bf16(f0) | ((uint32_t)f_to_bf16(f1) << 16);
        pk2.y = (uint32_t)f_to_bf16(f2) | ((uint32_t)f_to_bf16(f3) << 16);
        *(uint2*)((uint8_t*)Txb + (size_t)dst * sb + ro) = pk2;
    }
}

// ---------- GEMM: relu(A[M,640] @ Wt^T + bias), bf16 MFMA, BM=128 tile ----------
#define BM 128
#define BK 64
#define LDT 72
#define LDC 132

__global__ void __launch_bounds__(256) k_gemm(
        const uint16_t* __restrict__ A, size_t sstride,   // slot-major A; u16 per slot
        const uint16_t* __restrict__ Bt,
        const float* __restrict__ bias,
        uint16_t* __restrict__ out2b,              // bf16 slot0 (stride 128) or null
        float* __restrict__ pooled,                // fused pool accum or null
        const int* __restrict__ batch,
        int M, int Kdim) {
    __shared__ uint16_t smem[BM * LDT + 128 * LDT];
    uint16_t* As = smem;
    uint16_t* Bs = smem + BM * LDT;
    uint16_t* Ct = smem;
    int t = threadIdx.x;
    int w = t >> 6, lane = t & 63;
    int row0 = blockIdx.x * BM;
    int mrow = (w >> 1) * 64, ncol = (w & 1) * 64;

    int ar[4], akc[4];
#pragma unroll
    for (int rep = 0; rep < 4; rep++) {
        int d = rep * 256 + t;
        ar[rep] = d >> 3; akc[rep] = d & 7;
    }

    f32x4 acc[4][4];
#pragma unroll
    for (int i = 0; i < 4; i++)
#pragma unroll
        for (int j = 0; j < 4; j++) acc[i][j] = (f32x4){0.f, 0.f, 0.f, 0.f};

    bf16x8 pa[4], pb[4];
#pragma unroll
    for (int rep = 0; rep < 4; rep++) {
        int grow = row0 + ar[rep];
        int kk = akc[rep] * 8;
        bf16x8 va = {0, 0, 0, 0, 0, 0, 0, 0};
        if (grow < M)
            va = *(const bf16x8*)(A + (size_t)(kk >> 7) * sstride + (size_t)grow * 128 + (kk & 127));
        pa[rep] = va;
        pb[rep] = *(const bf16x8*)(Bt + (size_t)ar[rep] * Kdim + kk);
    }

    for (int k0 = 0; k0 < Kdim; k0 += BK) {
#pragma unroll
        for (int rep = 0; rep < 4; rep++) {
            *(bf16x8*)(&As[ar[rep] * LDT + akc[rep] * 8]) = pa[rep];
            *(bf16x8*)(&Bs[ar[rep] * LDT + akc[rep] * 8]) = pb[rep];
        }
        __syncthreads();
        int kn = k0 + BK;
        if (kn < Kdim) {
#pragma unroll
            for (int rep = 0; rep < 4; rep++) {
                int grow = row0 + ar[rep];
                int kk = kn + akc[rep] * 8;
                bf16x8 va = {0, 0, 0, 0, 0, 0, 0, 0};
                if (grow < M)
                    va = *(const bf16x8*)(A + (size_t)(kk >> 7) * sstride + (size_t)grow * 128 + (kk & 127));
                pa[rep] = va;
                pb[rep] = *(const bf16x8*)(Bt + (size_t)ar[rep] * Kdim + kk);
            }
        }
#pragma unroll
        for (int ks = 0; ks < BK; ks += 32) {
            bf16x8 af[4], bfr[4];
#pragma unroll
            for (int i = 0; i < 4; i++) {
                int r = mrow + i * 16 + (lane & 15);
                af[i] = *(const bf16x8*)(&As[r * LDT + ks + (lane >> 4) * 8]);
            }
#pragma unroll
            for (int j = 0; j < 4; j++) {
                int c = ncol + j * 16 + (lane & 15);
                bfr[j] = *(const bf16x8*)(&Bs[c * LDT + ks + (lane >> 4) * 8]);
            }
#pragma unroll
            for (int i = 0; i < 4; i++)
#pragma unroll
                for (int j = 0; j < 4; j++)
                    acc[i][j] = __builtin_amdgcn_mfma_f32_16x16x32_bf16(af[i], bfr[j], acc[i][j], 0, 0, 0);
        }
        __syncthreads();
    }

    // bias + relu -> bf16 into LDS
#pragma unroll
    for (int j = 0; j < 4; j++) {
        int c = ncol + j * 16 + (lane & 15);
        float bv = bias[c];
#pragma unroll
        for (int i = 0; i < 4; i++) {
            int rloc = mrow + i * 16 + (lane >> 4) * 4;
#pragma unroll
            for (int r = 0; r < 4; r++) {
                float v = acc[i][j][r] + bv;
                v = v > 0.f ? v : 0.f;
                Ct[(rloc + r) * LDC + c] = f_to_bf16(v);
            }
        }
    }
    __syncthreads();

    if (out2b) {
#pragma unroll
        for (int rep = 0; rep < 8; rep++) {
            int d = rep * 256 + t;
            int r = d >> 4, c8 = (d & 15) * 8;
            int grow = row0 + r;
            if (grow < M) {
                bf16x8 v = *(const bf16x8*)(&Ct[r * LDC + c8]);
                *(bf16x8*)(out2b + (size_t)grow * 128 + c8) = v;
            }
        }
    }
    if (pooled) {
        // fused mean-pool accumulation: thread t covers feature f = t&127,
        // rows [ (t>>7)*64, +64 ); batch sorted -> segmented flush
        int f = t & 127, r0 = (t >> 7) * 64;
        float accp = 0.f;
        int curb = -1;
        for (int r = r0; r < r0 + 64; ++r) {
            int grow = row0 + r;
            if (grow >= M) break;
            int b = batch[grow];
            if (b != curb) {
                if (curb >= 0) atomicAdd(&pooled[curb * 128 + f], accp);
                accp = 0.f; curb = b;
            }
            accp += __uint_as_float(((uint32_t)Ct[r * LDC + f]) << 16);
        }
        if (curb >= 0) atomicAdd(&pooled[curb * 128 + f], accp);
    }
}

// ---------- final linear (counts via binary search on sorted batch) ----------
__global__ void k_final(const float* __restrict__ pooled, const int* __restrict__ batch,
                        const float* __restrict__ Wlin, const float* __restrict__ blin,
                        float* __restrict__ out, int N, int B_, int C_) {
    __shared__ int cnt[64];
    int t = threadIdx.x;
    if (t < B_) {
        auto lb = [&](int v) {
            int lo = 0, hi = N;
            while (lo < hi) {
                int mid = (lo + hi) >> 1;
                if (batch[mid] < v) lo = mid + 1; else hi = mid;
            }
            return lo;
        };
        cnt[t] = lb(t + 1) - lb(t);
    }
    __syncthreads();
    if (t < B_ * C_) {
        int b = t / C_, c = t % C_;
        float inv = 1.f / fmaxf((float)cnt[b], 1.f);
        float acc = blin[c];
        for (int f = 0; f < 128; ++f) acc += pooled[b * 128 + f] * inv * Wlin[f * C_ + c];
        out[t] = acc;
    }
}

// ---------- launch ----------
extern "C" void kernel_launch(void* const* d_in, const int* in_sizes, int n_in,
                              void* d_out, int out_size, void* d_ws, size_t ws_size,
                              hipStream_t stream) {
    const float* x    = (const float*)d_in[0];
    const int*   edge = (const int*)d_in[1];
    const int*   batch= (const int*)d_in[2];
    const float* lam  = (const float*)d_in[3];
    const float* W1   = (const float*)d_in[4];
    const float* b1   = (const float*)d_in[5];
    const float* W2   = (const float*)d_in[6];
    const float* b2   = (const float*)d_in[7];
    const float* Wlin = (const float*)d_in[8];
    const float* blin = (const float*)d_in[9];
    const int E  = in_sizes[1] / 2;
    const int N  = in_sizes[2];
    const int B_ = in_sizes[3];
    const int* row = edge;
    const int* col = edge + E;

    char* ws = (char*)d_ws;
    size_t off = 0;
    auto take = [&](size_t bytes) -> char* {
        char* p = ws + off;
        off = (off + bytes + 255) & ~(size_t)255;
        return p;
    };
    uint16_t* Txb    = (uint16_t*)take((size_t)5 * (N + 1) * 128 * 2);   // 64MB
    uint32_t* ew     = (uint32_t*)take(((size_t)E + 8 * (size_t)N) * 4);
    int*      deg    = (int*)take((size_t)N * 4);
    int*      offs   = (int*)take((size_t)(N + 1) * 4);
    float*    dis    = (float*)take((size_t)N * 4);
    float*    diag   = (float*)take((size_t)N * 4);
    uint4*    nh     = (uint4*)take((size_t)N * 16);
    uint16_t* Wt1    = (uint16_t*)take((size_t)128 * 640 * 2);
    uint16_t* Wt2    = (uint16_t*)take((size_t)128 * 640 * 2);
    float*    pooled = (float*)take((size_t)B_ * 128 * 4);   // 256-aligned size
    int*      bhist  = (int*)take(257 * 4);                  // contiguous after pooled
    int*      gbase  = (int*)take(257 * 4);
    int*      gcur   = (int*)take(257 * 4);
    const int nb = (N + 255) / 256;
    int*      psum   = (int*)take((size_t)nb * 4);
    // bout aliased into Txb slot-4 region (12.8MB >= E*4B; slot 4 is only
    // written by the 4th lhat pass, long after bout's last read in k_ew;
    // castx's sentinel write (row N, end of slot) is beyond bout's 3.2MB)
    uint32_t* bout   = (uint32_t*)((char*)Txb + (size_t)4 * (N + 1) * 256);

    // one fill covers pooled (B_*512 bytes, 256-multiple) + bhist
    hipMemsetAsync(pooled, 0, (size_t)B_ * 128 * 4 + 257 * 4, stream);

    const int nchunks = (E + BINCH - 1) / BINCH;

    k_bhist<<<112, 256, 0, stream>>>(row, bhist, E);
    k_bscan<<<1, 256, 0, stream>>>(bhist, gbase, gcur, nb);
    k_bin<<<nchunks, 256, 0, stream>>>(row, col, gcur, bout, E);
    k_deg2<<<nb, 256, 0, stream>>>(bout, gbase, deg, psum, N);
    k_offs<<<nb, 256, 0, stream>>>(deg, psum, offs, batch, lam, dis, diag, nh, N, nb);
    k_ew<<<nb, 256, 0, stream>>>(bout, gbase, offs, dis, diag, ew, N);
    k_prepw<<<(2 * 128 * 640) / 256, 256, 0, stream>>>(W1, Wt1, W2, Wt2);
    k_castx<<<(N + 4) / 4, 256, 0, stream>>>(x, Txb, N);   // covers node N (sentinels)

    const int lblocks = (N + 3) / 4;
    const int gblocks = (N + BM - 1) / BM;
    const size_t ss = (size_t)(N + 1) * 128;               // u16 per slot

    // layer 1
    k_lhat<<<lblocks, 256, 0, stream>>>(Txb, nh, ew, N, 0, 1, 0, 1.f, 0);
    k_lhat<<<lblocks, 256, 0, stream>>>(Txb, nh, ew, N, 1, 2, 0, 2.f, 1);
    k_lhat<<<lblocks, 256, 0, stream>>>(Txb, nh, ew, N, 2, 3, 1, 2.f, 1);
    k_lhat<<<lblocks, 256, 0, stream>>>(Txb, nh, ew, N, 3, 4, 2, 2.f, 1);
    k_gemm<<<gblocks, 256, 0, stream>>>(Txb, ss, Wt1, b1,
                                        Txb /* slot 0 */, (float*)nullptr, batch, N, 640);

    // layer 2
    k_lhat<<<lblocks, 256, 0, stream>>>(Txb, nh, ew, N, 0, 1, 0, 1.f, 0);
    k_lhat<<<lblocks, 256, 0, stream>>>(Txb, nh, ew, N, 1, 2, 0, 2.f, 1);
    k_lhat<<<lblocks, 256, 0, stream>>>(Txb, nh, ew, N, 2, 3, 1, 2.f, 1);
    k_lhat<<<lblocks, 256, 0, stream>>>(Txb, nh, ew, N, 3, 4, 2, 2.f, 1);
    k_gemm<<<gblocks, 256, 0, stream>>>(Txb, ss, Wt2, b2,
                                        (uint16_t*)nullptr, pooled, batch, N, 640);

    k_final<<<1, 128, 0, stream>>>(pooled, batch, Wlin, blin, (float*)d_out, N, B_, 10);
}

// Round 7
// 468.466 us; speedup vs baseline: 2.6490x; 1.0032x over previous
//
#include <hip/hip_runtime.h>
#include <stdint.h>

// ---------- helpers ----------
typedef __attribute__((ext_vector_type(8))) short bf16x8;
typedef __attribute__((ext_vector_type(4))) float f32x4;

__device__ __forceinline__ float bf16lo_to_f(uint32_t u) { return __uint_as_float(u << 16); }
__device__ __forceinline__ float bf16hi_to_f(uint32_t u) { return __uint_as_float(u & 0xffff0000u); }
__device__ __forceinline__ uint16_t f_to_bf16(float f) {
    uint32_t u = __float_as_uint(f);
    uint32_t r = u + 0x7fff + ((u >> 16) & 1);   // round-to-nearest-even
    return (uint16_t)(r >> 16);
}

// Layouts:
//  Txb : bf16 [5][N+1][128] -- Chebyshev state, slot-major, 256B rows; row N = 0
//  ew  : u32 [E + 8N] -- {col u16 | bf16(w) << 16}; packet of 8 edges stored as
//        [h0e0 h0e1 h0e2 h0e3 | h1e0 h1e1 h1e2 h1e3]; half-wave h reads ONE uint4.
//  nh  : uint4 [N] -- {beg, end, bits(diag), 0} packed node header (1 line)

#define BINCH 4096

// fused: bhist + prepw + castx + sentinel zeroing -- mutually independent work
__global__ void __launch_bounds__(256) k_pre1(
        const int* __restrict__ row, int* __restrict__ bhist,
        const float* __restrict__ W1, uint16_t* __restrict__ Wt1,
        const float* __restrict__ W2, uint16_t* __restrict__ Wt2,
        const float* __restrict__ x, uint16_t* __restrict__ Txb,
        int E, int N) {
    __shared__ int sh[256];
    int t = threadIdx.x, b = blockIdx.x;
    int gstride = gridDim.x * 256;
    // bhist
    sh[t] = 0;
    __syncthreads();
    for (int e = b * 256 + t; e < E; e += gstride)
        atomicAdd(&sh[row[e] >> 8], 1);
    __syncthreads();
    if (sh[t]) atomicAdd(&bhist[t], sh[t]);
    // prepw
    for (int i = b * 256 + t; i < 2 * 128 * 640; i += gstride) {
        int ii = i;
        const float* W = W1; uint16_t* Wt = Wt1;
        if (ii >= 128 * 640) { ii -= 128 * 640; W = W2; Wt = Wt2; }
        int o = ii / 640, kk = ii % 640;
        Wt[(size_t)o * 640 + kk] = f_to_bf16(W[(size_t)kk * 128 + o]);
    }
    // castx (x fp32 -> Txb slot 0 bf16)
    {
        int lane = t & 63;
        int gw = b * 4 + (t >> 6);
        int tw = gridDim.x * 4;
        for (int n = gw; n < N; n += tw) {
            float2 v = ((const float2*)x)[(size_t)n * 64 + lane];
            uint32_t p = (uint32_t)f_to_bf16(v.x) | ((uint32_t)f_to_bf16(v.y) << 16);
            ((uint32_t*)Txb)[(size_t)n * 64 + lane] = p;
        }
    }
    // sentinel rows (row N of all 5 slots = 0); block 0 only
    if (b == 0) {
        int lane = t & 63;
        size_t ss32 = (size_t)(N + 1) * 64;
        for (int s = t >> 6; s < 5; s += 4)
            ((uint32_t*)Txb)[(size_t)s * ss32 + (size_t)N * 64 + lane] = 0u;
    }
}

// scan bucket counts -> gbase/gcur
__global__ void k_bscan(const int* __restrict__ bhist, int* __restrict__ gbase,
                        int* __restrict__ gcur, int nbk) {
    __shared__ int sh[256];
    int t = threadIdx.x;
    int v = t < nbk ? bhist[t] : 0;
    sh[t] = v;
    __syncthreads();
    for (int o = 1; o < 256; o <<= 1) {
        int u = (t >= o) ? sh[t - o] : 0;
        __syncthreads();
        sh[t] += u;
        __syncthreads();
    }
    gbase[t] = sh[t] - v;
    gcur[t] = sh[t] - v;
    if (t == 255) gbase[256] = sh[255];
}

// bin edges into bucket-sorted list; entry = (row&255) | (col<<8)
__global__ void __launch_bounds__(256) k_bin(const int* __restrict__ row,
        const int* __restrict__ col, int* __restrict__ gcur,
        uint32_t* __restrict__ bout, int E) {
    __shared__ uint32_t stage[BINCH];
    __shared__ int hist[256], hscan[256], hcur[256], gofs[256];
    int t = threadIdx.x;
    int e0 = blockIdx.x * BINCH;
    int ecnt = min(BINCH, E - e0);
    hist[t] = 0;
    __syncthreads();
    for (int i = t; i < ecnt; i += 256)
        atomicAdd(&hist[row[e0 + i] >> 8], 1);
    __syncthreads();
    int v = hist[t];
    hscan[t] = v;
    __syncthreads();
    for (int o = 1; o < 256; o <<= 1) {
        int u = (t >= o) ? hscan[t - o] : 0;
        __syncthreads();
        hscan[t] += u;
        __syncthreads();
    }
    hcur[t] = hscan[t] - v;
    __syncthreads();
    for (int i = t; i < ecnt; i += 256) {
        int r = row[e0 + i];
        int p = atomicAdd(&hcur[r >> 8], 1);
        stage[p] = (uint32_t)(r & 255) | ((uint32_t)col[e0 + i] << 8);
    }
    __syncthreads();
    if (v > 0) gofs[t] = atomicAdd(&gcur[t], v);
    __syncthreads();
    for (int i = t; i < ecnt; i += 256) {
        int lo = 0, hi = 255;
        while (lo < hi) { int mid = (lo + hi) >> 1; if (hscan[mid] > i) hi = mid; else lo = mid + 1; }
        int b = lo;
        int local = i - (hscan[b] - hist[b]);
        bout[gofs[b] + local] = stage[i];
    }
}

// per-node degree from bucket lists, fused with padded per-block sum (psum)
__global__ void __launch_bounds__(256) k_deg2(const uint32_t* __restrict__ bout,
        const int* __restrict__ gbase, int* __restrict__ deg,
        int* __restrict__ psum, int N) {
    __shared__ int cnt[256];
    __shared__ int red[256];
    int t = threadIdx.x, b = blockIdx.x;
    cnt[t] = 0;
    __syncthreads();
    int s = gbase[b], epos = gbase[b + 1];
    for (int i = s + t; i < epos; i += 256)
        atomicAdd(&cnt[bout[i] & 255], 1);
    __syncthreads();
    int n = b * 256 + t;
    int d = cnt[t];
    if (n < N) deg[n] = d;
    red[t] = (n < N) ? ((d + 7) & ~7) : 0;
    __syncthreads();
    for (int o = 128; o > 0; o >>= 1) {
        if (t < o) red[t] += red[t + o];
        __syncthreads();
    }
    if (t == 0) psum[b] = red[0];
}

// offs + dis/diag + packed node header nh
__global__ void k_offs(const int* __restrict__ deg, const int* __restrict__ psum,
                       int* __restrict__ offs,
                       const int* __restrict__ batch, const float* __restrict__ lam,
                       float* __restrict__ dis, float* __restrict__ diag,
                       uint4* __restrict__ nh,
                       int N, int nb) {
    __shared__ int pre[256];
    __shared__ int sh[256];
    int t = threadIdx.x, b = blockIdx.x;
    pre[t] = (t < b) ? psum[t] : 0;
    __syncthreads();
    for (int o = 128; o > 0; o >>= 1) {
        if (t < o) pre[t] += pre[t + o];
        __syncthreads();
    }
    int base = pre[0];
    __syncthreads();
    int idx = b * 256 + t;
    int d = idx < N ? deg[idx] : 0;
    int v = (d + 7) & ~7;
    sh[t] = v;
    __syncthreads();
    for (int o = 1; o < 256; o <<= 1) {
        int u = (t >= o) ? sh[t - o] : 0;
        __syncthreads();
        sh[t] += u;
        __syncthreads();
    }
    if (idx < N) {
        int beg = base + sh[t] - v;
        float dgv = 2.f / lam[batch[idx]] - 1.f;
        offs[idx] = beg;
        dis[idx] = d > 0 ? rsqrtf((float)d) : 0.f;
        diag[idx] = dgv;
        nh[idx] = make_uint4((uint32_t)beg, (uint32_t)(base + sh[t]),
                             __float_as_uint(dgv), 0u);
    }
    if (b == nb - 1 && t == 255) offs[N] = base + sh[255];
}

// final scatter: packed 4B edge entries {col u16 | bf16(w)<<16} in half-split
// packet order: idx i within node -> pos = (i&~7) + ((i&1)<<2) + ((i>>1)&3)
__global__ void __launch_bounds__(256) k_ew(const uint32_t* __restrict__ bout,
        const int* __restrict__ gbase, const int* __restrict__ offs,
        const float* __restrict__ dis, const float* __restrict__ diag,
        uint32_t* __restrict__ ew, int N) {
    __shared__ int cur[256];
    __shared__ int bs0[256];
    __shared__ float srw[256];        // per-local-row  -dis[r]*(diag[r]+1)
    int t = threadIdx.x, b = blockIdx.x;
    int n = b * 256 + t;
    int o0 = n < N ? offs[n] : 0;
    cur[t] = 0;
    bs0[t] = o0;
    srw[t] = (n < N) ? (-dis[n] * (diag[n] + 1.0f)) : 0.f;
    __syncthreads();
    int s = gbase[b], epos = gbase[b + 1];
    for (int i = s + t; i < epos; i += 256) {
        uint32_t v = bout[i];
        int r = (int)(v & 255u);
        int c = (int)(v >> 8);
        int idx = atomicAdd(&cur[r], 1);
        float w = srw[r] * dis[c];
        int pos = bs0[r] + (idx & ~7) + ((idx & 1) << 2) + ((idx >> 1) & 3);
        ew[pos] = (uint32_t)c | ((uint32_t)f_to_bf16(w) << 16);
    }
    __syncthreads();
    if (n < N) {
        int cnt = cur[t];
        int pe = (cnt + 7) & ~7;
        for (int i = cnt; i < pe; i++) {
            int pos = o0 + (i & ~7) + ((i & 1) << 2) + ((i >> 1) & 3);
            ew[pos] = (uint32_t)N;            // w = 0 (bf16 zero in high bits)
        }
    }
}

// =========================================================================
// k_lhat: dst = alpha*(sum_e w_e*src[col] + diag*src[n]) - (use_prev?prev:0)
// bf16 state; half-wave edge split; 2-PACKET-DEEP batching: both packets'
// descriptors issued together (dependent only on nh), then all 8 q-loads in
// flight, then FMA. Serial chain depth = 3 memory levels for 16 edges.
// =========================================================================
__global__ void __launch_bounds__(256) k_lhat(uint16_t* __restrict__ Txb,
        const uint4* __restrict__ nh, const uint32_t* __restrict__ ew,
        int N,
        int src, int dst, int prev, float alpha, int use_prev) {
    int n = (blockIdx.x * blockDim.x + threadIdx.x) >> 6;
    int lane = threadIdx.x & 63;
    if (n >= N) return;
    int h = lane >> 5, g = lane & 31;
    size_t sb = (size_t)(N + 1) * 256;           // bytes per slot
    const uint8_t* srcs = (const uint8_t*)Txb + (size_t)src * sb;
    uint32_t g8 = (uint32_t)g * 8;
    uint4 hh = nh[n];                            // level 1
    int e = (int)hh.x, end = (int)hh.y;
    float dgn = __uint_as_float(hh.z);
    float a0 = 0.f, a1 = 0.f, a2 = 0.f, a3 = 0.f;
    int npk = (end - e) >> 3;
    const uint4* ep = (const uint4*)(ew + e + h * 4);  // half h's desc in packet pk: ep[pk*2]
    int pk = 0;
    while (pk < npk) {
        if (npk - pk >= 2) {
            uint4 c0 = ep[pk * 2];               // level 2 (both issued together)
            uint4 c1 = ep[pk * 2 + 2];
            uint2 q[8]; float w[8];
#pragma unroll
            for (int u = 0; u < 4; u++) {        // level 3: 8 q-loads in flight
                uint32_t cw = (&c0.x)[u];
                w[u] = __uint_as_float(cw & 0xffff0000u);
                q[u] = *(const uint2*)(srcs + ((cw & 0xffffu) << 8) + g8);
            }
#pragma unroll
            for (int u = 0; u < 4; u++) {
                uint32_t cw = (&c1.x)[u];
                w[4 + u] = __uint_as_float(cw & 0xffff0000u);
                q[4 + u] = *(const uint2*)(srcs + ((cw & 0xffffu) << 8) + g8);
            }
#pragma unroll
            for (int u = 0; u < 8; u++) {
                a0 = fmaf(w[u], bf16lo_to_f(q[u].x), a0);
                a1 = fmaf(w[u], bf16hi_to_f(q[u].x), a1);
                a2 = fmaf(w[u], bf16lo_to_f(q[u].y), a2);
                a3 = fmaf(w[u], bf16hi_to_f(q[u].y), a3);
            }
            pk += 2;
        } else {
            uint4 c0 = ep[pk * 2];
#pragma unroll
            for (int u = 0; u < 4; u++) {
                uint32_t cw = (&c0.x)[u];
                float w = __uint_as_float(cw & 0xffff0000u);
                uint2 q = *(const uint2*)(srcs + ((cw & 0xffffu) << 8) + g8);
                a0 = fmaf(w, bf16lo_to_f(q.x), a0);
                a1 = fmaf(w, bf16hi_to_f(q.x), a1);
                a2 = fmaf(w, bf16lo_to_f(q.y), a2);
                a3 = fmaf(w, bf16hi_to_f(q.y), a3);
            }
            pk += 1;
        }
    }
    // combine the two edge-halves
    a0 += __shfl_xor(a0, 32);
    a1 += __shfl_xor(a1, 32);
    a2 += __shfl_xor(a2, 32);
    a3 += __shfl_xor(a3, 32);
    if (h == 0) {
        size_t ro = (size_t)n * 256 + g8;
        uint2 qs = *(const uint2*)(srcs + ro);
        a0 = fmaf(dgn, bf16lo_to_f(qs.x), a0);
        a1 = fmaf(dgn, bf16hi_to_f(qs.x), a1);
        a2 = fmaf(dgn, bf16lo_to_f(qs.y), a2);
        a3 = fmaf(dgn, bf16hi_to_f(qs.y), a3);
        float f0 = alpha * a0, f1 = alpha * a1, f2 = alpha * a2, f3 = alpha * a3;
        if (use_prev) {
            uint2 qp = *(const uint2*)((const uint8_t*)Txb + (size_t)prev * sb + ro);
            f0 -= bf16lo_to_f(qp.x);
            f1 -= bf16hi_to_f(qp.x);
            f2 -= bf16lo_to_f(qp.y);
            f3 -= bf16hi_to_f(qp.y);
        }
        uint2 pk2;
        pk2.x = (uint32_t)f_to_bf16(f0) | ((uint32_t)f_to_bf16(f1) << 16);
        pk2.y = (uint32_t)f_to_bf16(f2) | ((uint32_t)f_to_bf16(f3) << 16);
        *(uint2*)((uint8_t*)Txb + (size_t)dst * sb + ro) = pk2;
    }
}

// ---------- GEMM: relu(A[M,640] @ Wt^T + bias), bf16 MFMA, BM=128 tile ----------
#define BM 128
#define BK 64
#define LDT 72
#define LDC 132

__global__ void __launch_bounds__(256) k_gemm(
        const uint16_t* __restrict__ A, size_t sstride,   // slot-major A; u16 per slot
        const uint16_t* __restrict__ Bt,
        const float* __restrict__ bias,
        uint16_t* __restrict__ out2b,              // bf16 slot0 (stride 128) or null
        float* __restrict__ pooled,                // fused pool accum or null
        const int* __restrict__ batch,
        int M, int Kdim) {
    __shared__ uint16_t smem[BM * LDT + 128 * LDT];
    uint16_t* As = smem;
    uint16_t* Bs = smem + BM * LDT;
    uint16_t* Ct = smem;
    int t = threadIdx.x;
    int w = t >> 6, lane = t & 63;
    int row0 = blockIdx.x * BM;
    int mrow = (w >> 1) * 64, ncol = (w & 1) * 64;

    int ar[4], akc[4];
#pragma unroll
    for (int rep = 0; rep < 4; rep++) {
        int d = rep * 256 + t;
        ar[rep] = d >> 3; akc[rep] = d & 7;
    }

    f32x4 acc[4][4];
#pragma unroll
    for (int i = 0; i < 4; i++)
#pragma unroll
        for (int j = 0; j < 4; j++) acc[i][j] = (f32x4){0.f, 0.f, 0.f, 0.f};

    bf16x8 pa[4], pb[4];
#pragma unroll
    for (int rep = 0; rep < 4; rep++) {
        int grow = row0 + ar[rep];
        int kk = akc[rep] * 8;
        bf16x8 va = {0, 0, 0, 0, 0, 0, 0, 0};
        if (grow < M)
            va = *(const bf16x8*)(A + (size_t)(kk >> 7) * sstride + (size_t)grow * 128 + (kk & 127));
        pa[rep] = va;
        pb[rep] = *(const bf16x8*)(Bt + (size_t)ar[rep] * Kdim + kk);
    }

    for (int k0 = 0; k0 < Kdim; k0 += BK) {
#pragma unroll
        for (int rep = 0; rep < 4; rep++) {
            *(bf16x8*)(&As[ar[rep] * LDT + akc[rep] * 8]) = pa[rep];
            *(bf16x8*)(&Bs[ar[rep] * LDT + akc[rep] * 8]) = pb[rep];
        }
        __syncthreads();
        int kn = k0 + BK;
        if (kn < Kdim) {
#pragma unroll
            for (int rep = 0; rep < 4; rep++) {
                int grow = row0 + ar[rep];
                int kk = kn + akc[rep] * 8;
                bf16x8 va = {0, 0, 0, 0, 0, 0, 0, 0};
                if (grow < M)
                    va = *(const bf16x8*)(A + (size_t)(kk >> 7) * sstride + (size_t)grow * 128 + (kk & 127));
                pa[rep] = va;
                pb[rep] = *(const bf16x8*)(Bt + (size_t)ar[rep] * Kdim + kk);
            }
        }
#pragma unroll
        for (int ks = 0; ks < BK; ks += 32) {
            bf16x8 af[4], bfr[4];
#pragma unroll
            for (int i = 0; i < 4; i++) {
                int r = mrow + i * 16 + (lane & 15);
                af[i] = *(const bf16x8*)(&As[r * LDT + ks + (lane >> 4) * 8]);
            }
#pragma unroll
            for (int j = 0; j < 4; j++) {
                int c = ncol + j * 16 + (lane & 15);
                bfr[j] = *(const bf16x8*)(&Bs[c * LDT + ks + (lane >> 4) * 8]);
            }
#pragma unroll
            for (int i = 0; i < 4; i++)
#pragma unroll
                for (int j = 0; j < 4; j++)
                    acc[i][j] = __builtin_amdgcn_mfma_f32_16x16x32_bf16(af[i], bfr[j], acc[i][j], 0, 0, 0);
        }
        __syncthreads();
    }

    // bias + relu -> bf16 into LDS
#pragma unroll
    for (int j = 0; j < 4; j++) {
        int c = ncol + j * 16 + (lane & 15);
        float bv = bias[c];
#pragma unroll
        for (int i = 0; i < 4; i++) {
            int rloc = mrow + i * 16 + (lane >> 4) * 4;
#pragma unroll
            for (int r = 0; r < 4; r++) {
                float v = acc[i][j][r] + bv;
                v = v > 0.f ? v : 0.f;
                Ct[(rloc + r) * LDC + c] = f_to_bf16(v);
            }
        }
    }
    __syncthreads();

    if (out2b) {
#pragma unroll
        for (int rep = 0; rep < 8; rep++) {
            int d = rep * 256 + t;
            int r = d >> 4, c8 = (d & 15) * 8;
            int grow = row0 + r;
            if (grow < M) {
                bf16x8 v = *(const bf16x8*)(&Ct[r * LDC + c8]);
                *(bf16x8*)(out2b + (size_t)grow * 128 + c8) = v;
            }
        }
    }
    if (pooled) {
        // fused mean-pool accumulation: thread t covers feature f = t&127,
        // rows [ (t>>7)*64, +64 ); batch sorted -> segmented flush
        int f = t & 127, r0 = (t >> 7) * 64;
        float accp = 0.f;
        int curb = -1;
        for (int r = r0; r < r0 + 64; ++r) {
            int grow = row0 + r;
            if (grow >= M) break;
            int b = batch[grow];
            if (b != curb) {
                if (curb >= 0) atomicAdd(&pooled[curb * 128 + f], accp);
                accp = 0.f; curb = b;
            }
            accp += __uint_as_float(((uint32_t)Ct[r * LDC + f]) << 16);
        }
        if (curb >= 0) atomicAdd(&pooled[curb * 128 + f], accp);
    }
}

// ---------- final linear (counts via binary search on sorted batch) ----------
__global__ void k_final(const float* __restrict__ pooled, const int* __restrict__ batch,
                        const float* __restrict__ Wlin, const float* __restrict__ blin,
                        float* __restrict__ out, int N, int B_, int C_) {
    __shared__ int cnt[64];
    int t = threadIdx.x;
    if (t < B_) {
        auto lb = [&](int v) {
            int lo = 0, hi = N;
            while (lo < hi) {
                int mid = (lo + hi) >> 1;
                if (batch[mid] < v) lo = mid + 1; else hi = mid;
            }
            return lo;
        };
        cnt[t] = lb(t + 1) - lb(t);
    }
    __syncthreads();
    if (t < B_ * C_) {
        int b = t / C_, c = t % C_;
        float inv = 1.f / fmaxf((float)cnt[b], 1.f);
        float acc = blin[c];
        for (int f = 0; f < 128; ++f) acc += pooled[b * 128 + f] * inv * Wlin[f * C_ + c];
        out[t] = acc;
    }
}

// ---------- launch ----------
extern "C" void kernel_launch(void* const* d_in, const int* in_sizes, int n_in,
                              void* d_out, int out_size, void* d_ws, size_t ws_size,
                              hipStream_t stream) {
    const float* x    = (const float*)d_in[0];
    const int*   edge = (const int*)d_in[1];
    const int*   batch= (const int*)d_in[2];
    const float* lam  = (const float*)d_in[3];
    const float* W1   = (const float*)d_in[4];
    const float* b1   = (const float*)d_in[5];
    const float* W2   = (const float*)d_in[6];
    const float* b2   = (const float*)d_in[7];
    const float* Wlin = (const float*)d_in[8];
    const float* blin = (const float*)d_in[9];
    const int E  = in_sizes[1] / 2;
    const int N  = in_sizes[2];
    const int B_ = in_sizes[3];
    const int* row = edge;
    const int* col = edge + E;

    char* ws = (char*)d_ws;
    size_t off = 0;
    auto take = [&](size_t bytes) -> char* {
        char* p = ws + off;
        off = (off + bytes + 255) & ~(size_t)255;
        return p;
    };
    uint16_t* Txb    = (uint16_t*)take((size_t)5 * (N + 1) * 128 * 2);   // 64MB
    uint32_t* ew     = (uint32_t*)take(((size_t)E + 8 * (size_t)N) * 4);
    int*      deg    = (int*)take((size_t)N * 4);
    int*      offs   = (int*)take((size_t)(N + 1) * 4);
    float*    dis    = (float*)take((size_t)N * 4);
    float*    diag   = (float*)take((size_t)N * 4);
    uint4*    nh     = (uint4*)take((size_t)N * 16);
    uint16_t* Wt1    = (uint16_t*)take((size_t)128 * 640 * 2);
    uint16_t* Wt2    = (uint16_t*)take((size_t)128 * 640 * 2);
    float*    pooled = (float*)take((size_t)B_ * 128 * 4);   // 256-aligned size
    int*      bhist  = (int*)take(257 * 4);                  // contiguous after pooled
    int*      gbase  = (int*)take(257 * 4);
    int*      gcur   = (int*)take(257 * 4);
    const int nb = (N + 255) / 256;
    int*      psum   = (int*)take((size_t)nb * 4);
    // bout aliased into Txb slot-4 region (12.8MB >= E*4B; slot 4 is only
    // written by the 4th lhat pass, long after bout's last read in k_ew;
    // sentinel write of slot 4 (row N, offset 12.8MB into slot) is beyond
    // bout's 3.2MB extent)
    uint32_t* bout   = (uint32_t*)((char*)Txb + (size_t)4 * (N + 1) * 256);

    // one fill covers pooled (B_*512 bytes, 256-multiple) + bhist
    hipMemsetAsync(pooled, 0, (size_t)B_ * 128 * 4 + 257 * 4, stream);

    const int nchunks = (E + BINCH - 1) / BINCH;

    k_pre1<<<1024, 256, 0, stream>>>(row, bhist, W1, Wt1, W2, Wt2, x, Txb, E, N);
    k_bscan<<<1, 256, 0, stream>>>(bhist, gbase, gcur, nb);
    k_bin<<<nchunks, 256, 0, stream>>>(row, col, gcur, bout, E);
    k_deg2<<<nb, 256, 0, stream>>>(bout, gbase, deg, psum, N);
    k_offs<<<nb, 256, 0, stream>>>(deg, psum, offs, batch, lam, dis, diag, nh, N, nb);
    k_ew<<<nb, 256, 0, stream>>>(bout, gbase, offs, dis, diag, ew, N);

    const int lblocks = (N + 3) / 4;
    const int gblocks = (N + BM - 1) / BM;
    const size_t ss = (size_t)(N + 1) * 128;               // u16 per slot

    // layer 1
    k_lhat<<<lblocks, 256, 0, stream>>>(Txb, nh, ew, N, 0, 1, 0, 1.f, 0);
    k_lhat<<<lblocks, 256, 0, stream>>>(Txb, nh, ew, N, 1, 2, 0, 2.f, 1);
    k_lhat<<<lblocks, 256, 0, stream>>>(Txb, nh, ew, N, 2, 3, 1, 2.f, 1);
    k_lhat<<<lblocks, 256, 0, stream>>>(Txb, nh, ew, N, 3, 4, 2, 2.f, 1);
    k_gemm<<<gblocks, 256, 0, stream>>>(Txb, ss, Wt1, b1,
                                        Txb /* slot 0 */, (float*)nullptr, batch, N, 640);

    // layer 2
    k_lhat<<<lblocks, 256, 0, stream>>>(Txb, nh, ew, N, 0, 1, 0, 1.f, 0);
    k_lhat<<<lblocks, 256, 0, stream>>>(Txb, nh, ew, N, 1, 2, 0, 2.f, 1);
    k_lhat<<<lblocks, 256, 0, stream>>>(Txb, nh, ew, N, 2, 3, 1, 2.f, 1);
    k_lhat<<<lblocks, 256, 0, stream>>>(Txb, nh, ew, N, 3, 4, 2, 2.f, 1);
    k_gemm<<<gblocks, 256, 0, stream>>>(Txb, ss, Wt2, b2,
                                        (uint16_t*)nullptr, pooled, batch, N, 640);

    k_final<<<1, 128, 0, stream>>>(pooled, batch, Wlin, blin, (float*)d_out, N, B_, 10);
}

// Round 8
// 468.444 us; speedup vs baseline: 2.6491x; 1.0000x over previous
//
#include <hip/hip_runtime.h>
#include <stdint.h>

#ifndef __has_builtin
#define __has_builtin(x) 0
#endif

// ---------- helpers ----------
typedef __attribute__((ext_vector_type(8))) short bf16x8;
typedef __attribute__((ext_vector_type(4))) float f32x4;

__device__ __forceinline__ float bf16lo_to_f(uint32_t u) { return __uint_as_float(u << 16); }
__device__ __forceinline__ float bf16hi_to_f(uint32_t u) { return __uint_as_float(u & 0xffff0000u); }
__device__ __forceinline__ uint16_t f_to_bf16(float f) {
    uint32_t u = __float_as_uint(f);
    uint32_t r = u + 0x7fff + ((u >> 16) & 1);   // round-to-nearest-even
    return (uint16_t)(r >> 16);
}

// direct global->LDS DMA (16B/lane); lds must be wave-uniform base, dest = base + lane*16
__device__ __forceinline__ void dma16(const uint16_t* g, uint16_t* lds, int lane) {
#if __has_builtin(__builtin_amdgcn_global_load_lds)
    __builtin_amdgcn_global_load_lds((const __attribute__((address_space(1))) void*)g,
                                     (__attribute__((address_space(3))) void*)lds, 16, 0, 0);
#else
    *(bf16x8*)(lds + lane * 8) = *(const bf16x8*)g;
#endif
}

// Layouts:
//  Txb : bf16 [5][N+1][128] -- Chebyshev state, slot-major, 256B rows; row N = 0
//  ew  : u32 [E + 8N] -- {col u16 | bf16(w) << 16}; packet of 8 edges stored as
//        [h0e0 h0e1 h0e2 h0e3 | h1e0 h1e1 h1e2 h1e3]; half-wave h reads ONE uint4.
//  nh  : uint4 [N] -- {beg, end, bits(diag), 0} packed node header (1 line)

#define BINCH 4096

// fused: bhist + prepw + castx + sentinel zeroing -- mutually independent work
__global__ void __launch_bounds__(256) k_pre1(
        const int* __restrict__ row, int* __restrict__ bhist,
        const float* __restrict__ W1, uint16_t* __restrict__ Wt1,
        const float* __restrict__ W2, uint16_t* __restrict__ Wt2,
        const float* __restrict__ x, uint16_t* __restrict__ Txb,
        int E, int N) {
    __shared__ int sh[256];
    int t = threadIdx.x, b = blockIdx.x;
    int gstride = gridDim.x * 256;
    // bhist
    sh[t] = 0;
    __syncthreads();
    for (int e = b * 256 + t; e < E; e += gstride)
        atomicAdd(&sh[row[e] >> 8], 1);
    __syncthreads();
    if (sh[t]) atomicAdd(&bhist[t], sh[t]);
    // prepw
    for (int i = b * 256 + t; i < 2 * 128 * 640; i += gstride) {
        int ii = i;
        const float* W = W1; uint16_t* Wt = Wt1;
        if (ii >= 128 * 640) { ii -= 128 * 640; W = W2; Wt = Wt2; }
        int o = ii / 640, kk = ii % 640;
        Wt[(size_t)o * 640 + kk] = f_to_bf16(W[(size_t)kk * 128 + o]);
    }
    // castx (x fp32 -> Txb slot 0 bf16)
    {
        int lane = t & 63;
        int gw = b * 4 + (t >> 6);
        int tw = gridDim.x * 4;
        for (int n = gw; n < N; n += tw) {
            float2 v = ((const float2*)x)[(size_t)n * 64 + lane];
            uint32_t p = (uint32_t)f_to_bf16(v.x) | ((uint32_t)f_to_bf16(v.y) << 16);
            ((uint32_t*)Txb)[(size_t)n * 64 + lane] = p;
        }
    }
    // sentinel rows (row N of all 5 slots = 0); block 0 only
    if (b == 0) {
        int lane = t & 63;
        size_t ss32 = (size_t)(N + 1) * 64;
        for (int s = t >> 6; s < 5; s += 4)
            ((uint32_t*)Txb)[(size_t)s * ss32 + (size_t)N * 64 + lane] = 0u;
    }
}

// scan bucket counts -> gbase/gcur
__global__ void k_bscan(const int* __restrict__ bhist, int* __restrict__ gbase,
                        int* __restrict__ gcur, int nbk) {
    __shared__ int sh[256];
    int t = threadIdx.x;
    int v = t < nbk ? bhist[t] : 0;
    sh[t] = v;
    __syncthreads();
    for (int o = 1; o < 256; o <<= 1) {
        int u = (t >= o) ? sh[t - o] : 0;
        __syncthreads();
        sh[t] += u;
        __syncthreads();
    }
    gbase[t] = sh[t] - v;
    gcur[t] = sh[t] - v;
    if (t == 255) gbase[256] = sh[255];
}

// bin edges into bucket-sorted list; entry = (row&255) | (col<<8)
__global__ void __launch_bounds__(256) k_bin(const int* __restrict__ row,
        const int* __restrict__ col, int* __restrict__ gcur,
        uint32_t* __restrict__ bout, int E) {
    __shared__ uint32_t stage[BINCH];
    __shared__ int hist[256], hscan[256], hcur[256], gofs[256];
    int t = threadIdx.x;
    int e0 = blockIdx.x * BINCH;
    int ecnt = min(BINCH, E - e0);
    hist[t] = 0;
    __syncthreads();
    for (int i = t; i < ecnt; i += 256)
        atomicAdd(&hist[row[e0 + i] >> 8], 1);
    __syncthreads();
    int v = hist[t];
    hscan[t] = v;
    __syncthreads();
    for (int o = 1; o < 256; o <<= 1) {
        int u = (t >= o) ? hscan[t - o] : 0;
        __syncthreads();
        hscan[t] += u;
        __syncthreads();
    }
    hcur[t] = hscan[t] - v;
    __syncthreads();
    for (int i = t; i < ecnt; i += 256) {
        int r = row[e0 + i];
        int p = atomicAdd(&hcur[r >> 8], 1);
        stage[p] = (uint32_t)(r & 255) | ((uint32_t)col[e0 + i] << 8);
    }
    __syncthreads();
    if (v > 0) gofs[t] = atomicAdd(&gcur[t], v);
    __syncthreads();
    for (int i = t; i < ecnt; i += 256) {
        int lo = 0, hi = 255;
        while (lo < hi) { int mid = (lo + hi) >> 1; if (hscan[mid] > i) hi = mid; else lo = mid + 1; }
        int b = lo;
        int local = i - (hscan[b] - hist[b]);
        bout[gofs[b] + local] = stage[i];
    }
}

// per-node degree from bucket lists, fused with padded per-block sum (psum)
__global__ void __launch_bounds__(256) k_deg2(const uint32_t* __restrict__ bout,
        const int* __restrict__ gbase, int* __restrict__ deg,
        int* __restrict__ psum, int N) {
    __shared__ int cnt[256];
    __shared__ int red[256];
    int t = threadIdx.x, b = blockIdx.x;
    cnt[t] = 0;
    __syncthreads();
    int s = gbase[b], epos = gbase[b + 1];
    for (int i = s + t; i < epos; i += 256)
        atomicAdd(&cnt[bout[i] & 255], 1);
    __syncthreads();
    int n = b * 256 + t;
    int d = cnt[t];
    if (n < N) deg[n] = d;
    red[t] = (n < N) ? ((d + 7) & ~7) : 0;
    __syncthreads();
    for (int o = 128; o > 0; o >>= 1) {
        if (t < o) red[t] += red[t + o];
        __syncthreads();
    }
    if (t == 0) psum[b] = red[0];
}

// offs + dis/diag + packed node header nh
__global__ void k_offs(const int* __restrict__ deg, const int* __restrict__ psum,
                       int* __restrict__ offs,
                       const int* __restrict__ batch, const float* __restrict__ lam,
                       float* __restrict__ dis, float* __restrict__ diag,
                       uint4* __restrict__ nh,
                       int N, int nb) {
    __shared__ int pre[256];
    __shared__ int sh[256];
    int t = threadIdx.x, b = blockIdx.x;
    pre[t] = (t < b) ? psum[t] : 0;
    __syncthreads();
    for (int o = 128; o > 0; o >>= 1) {
        if (t < o) pre[t] += pre[t + o];
        __syncthreads();
    }
    int base = pre[0];
    __syncthreads();
    int idx = b * 256 + t;
    int d = idx < N ? deg[idx] : 0;
    int v = (d + 7) & ~7;
    sh[t] = v;
    __syncthreads();
    for (int o = 1; o < 256; o <<= 1) {
        int u = (t >= o) ? sh[t - o] : 0;
        __syncthreads();
        sh[t] += u;
        __syncthreads();
    }
    if (idx < N) {
        int beg = base + sh[t] - v;
        float dgv = 2.f / lam[batch[idx]] - 1.f;
        offs[idx] = beg;
        dis[idx] = d > 0 ? rsqrtf((float)d) : 0.f;
        diag[idx] = dgv;
        nh[idx] = make_uint4((uint32_t)beg, (uint32_t)(base + sh[t]),
                             __float_as_uint(dgv), 0u);
    }
    if (b == nb - 1 && t == 255) offs[N] = base + sh[255];
}

// final scatter: packed 4B edge entries {col u16 | bf16(w)<<16} in half-split
// packet order: idx i within node -> pos = (i&~7) + ((i&1)<<2) + ((i>>1)&3)
__global__ void __launch_bounds__(256) k_ew(const uint32_t* __restrict__ bout,
        const int* __restrict__ gbase, const int* __restrict__ offs,
        const float* __restrict__ dis, const float* __restrict__ diag,
        uint32_t* __restrict__ ew, int N) {
    __shared__ int cur[256];
    __shared__ int bs0[256];
    __shared__ float srw[256];        // per-local-row  -dis[r]*(diag[r]+1)
    int t = threadIdx.x, b = blockIdx.x;
    int n = b * 256 + t;
    int o0 = n < N ? offs[n] : 0;
    cur[t] = 0;
    bs0[t] = o0;
    srw[t] = (n < N) ? (-dis[n] * (diag[n] + 1.0f)) : 0.f;
    __syncthreads();
    int s = gbase[b], epos = gbase[b + 1];
    for (int i = s + t; i < epos; i += 256) {
        uint32_t v = bout[i];
        int r = (int)(v & 255u);
        int c = (int)(v >> 8);
        int idx = atomicAdd(&cur[r], 1);
        float w = srw[r] * dis[c];
        int pos = bs0[r] + (idx & ~7) + ((idx & 1) << 2) + ((idx >> 1) & 3);
        ew[pos] = (uint32_t)c | ((uint32_t)f_to_bf16(w) << 16);
    }
    __syncthreads();
    if (n < N) {
        int cnt = cur[t];
        int pe = (cnt + 7) & ~7;
        for (int i = cnt; i < pe; i++) {
            int pos = o0 + (i & ~7) + ((i & 1) << 2) + ((i >> 1) & 3);
            ew[pos] = (uint32_t)N;            // w = 0 (bf16 zero in high bits)
        }
    }
}

// =========================================================================
// k_lhat: dst = alpha*(sum_e w_e*src[col] + diag*src[n]) - (use_prev?prev:0)
// bf16 state; half-wave edge split; 2-packet-deep descriptor batching.
// (round-7 proven, byte-identical)
// =========================================================================
__global__ void __launch_bounds__(256) k_lhat(uint16_t* __restrict__ Txb,
        const uint4* __restrict__ nh, const uint32_t* __restrict__ ew,
        int N,
        int src, int dst, int prev, float alpha, int use_prev) {
    int n = (blockIdx.x * blockDim.x + threadIdx.x) >> 6;
    int lane = threadIdx.x & 63;
    if (n >= N) return;
    int h = lane >> 5, g = lane & 31;
    size_t sb = (size_t)(N + 1) * 256;           // bytes per slot
    const uint8_t* srcs = (const uint8_t*)Txb + (size_t)src * sb;
    uint32_t g8 = (uint32_t)g * 8;
    uint4 hh = nh[n];
    int e = (int)hh.x, end = (int)hh.y;
    float dgn = __uint_as_float(hh.z);
    float a0 = 0.f, a1 = 0.f, a2 = 0.f, a3 = 0.f;
    int npk = (end - e) >> 3;
    const uint4* ep = (const uint4*)(ew + e + h * 4);
    int pk = 0;
    while (pk < npk) {
        if (npk - pk >= 2) {
            uint4 c0 = ep[pk * 2];
            uint4 c1 = ep[pk * 2 + 2];
            uint2 q[8]; float w[8];
#pragma unroll
            for (int u = 0; u < 4; u++) {
                uint32_t cw = (&c0.x)[u];
                w[u] = __uint_as_float(cw & 0xffff0000u);
                q[u] = *(const uint2*)(srcs + ((cw & 0xffffu) << 8) + g8);
            }
#pragma unroll
            for (int u = 0; u < 4; u++) {
                uint32_t cw = (&c1.x)[u];
                w[4 + u] = __uint_as_float(cw & 0xffff0000u);
                q[4 + u] = *(const uint2*)(srcs + ((cw & 0xffffu) << 8) + g8);
            }
#pragma unroll
            for (int u = 0; u < 8; u++) {
                a0 = fmaf(w[u], bf16lo_to_f(q[u].x), a0);
                a1 = fmaf(w[u], bf16hi_to_f(q[u].x), a1);
                a2 = fmaf(w[u], bf16lo_to_f(q[u].y), a2);
                a3 = fmaf(w[u], bf16hi_to_f(q[u].y), a3);
            }
            pk += 2;
        } else {
            uint4 c0 = ep[pk * 2];
#pragma unroll
            for (int u = 0; u < 4; u++) {
                uint32_t cw = (&c0.x)[u];
                float w = __uint_as_float(cw & 0xffff0000u);
                uint2 q = *(const uint2*)(srcs + ((cw & 0xffffu) << 8) + g8);
                a0 = fmaf(w, bf16lo_to_f(q.x), a0);
                a1 = fmaf(w, bf16hi_to_f(q.x), a1);
                a2 = fmaf(w, bf16lo_to_f(q.y), a2);
                a3 = fmaf(w, bf16hi_to_f(q.y), a3);
            }
            pk += 1;
        }
    }
    a0 += __shfl_xor(a0, 32);
    a1 += __shfl_xor(a1, 32);
    a2 += __shfl_xor(a2, 32);
    a3 += __shfl_xor(a3, 32);
    if (h == 0) {
        size_t ro = (size_t)n * 256 + g8;
        uint2 qs = *(const uint2*)(srcs + ro);
        a0 = fmaf(dgn, bf16lo_to_f(qs.x), a0);
        a1 = fmaf(dgn, bf16hi_to_f(qs.x), a1);
        a2 = fmaf(dgn, bf16lo_to_f(qs.y), a2);
        a3 = fmaf(dgn, bf16hi_to_f(qs.y), a3);
        float f0 = alpha * a0, f1 = alpha * a1, f2 = alpha * a2, f3 = alpha * a3;
        if (use_prev) {
            uint2 qp = *(const uint2*)((const uint8_t*)Txb + (size_t)prev * sb + ro);
            f0 -= bf16lo_to_f(qp.x);
            f1 -= bf16hi_to_f(qp.x);
            f2 -= bf16lo_to_f(qp.y);
            f3 -= bf16hi_to_f(qp.y);
        }
        uint2 pk2;
        pk2.x = (uint32_t)f_to_bf16(f0) | ((uint32_t)f_to_bf16(f1) << 16);
        pk2.y = (uint32_t)f_to_bf16(f2) | ((uint32_t)f_to_bf16(f3) << 16);
        *(uint2*)((uint8_t*)Txb + (size_t)dst * sb + ro) = pk2;
    }
}

// ---------- GEMM: relu(A[M,640] @ Wt^T + bias), bf16 MFMA, BM=128 tile ----------
// Staging via global_load_lds (16B/lane DMA), LDS de-padded to 64 u16/row with
// XOR swizzle ((r&7)<<3) applied on the global source and the ds_read address
// (linear-dest + pre-swizzled-source pattern; kills the stride-128B bank conflict).
#define BM 128
#define BKS 64
#define LDC 132

__global__ void __launch_bounds__(256) k_gemm(
        const uint16_t* __restrict__ A, size_t sstride,   // slot-major A; u16 per slot
        const uint16_t* __restrict__ Bt,
        const float* __restrict__ bias,
        uint16_t* __restrict__ out2b,              // bf16 slot0 (stride 128) or null
        float* __restrict__ pooled,                // fused pool accum or null
        const int* __restrict__ batch,
        int M, int Kdim) {
    __shared__ uint16_t smem[128 * LDC];           // >= As(8192) + Bs(8192)
    uint16_t* As = smem;                           // [128][64] swizzled
    uint16_t* Bs = smem + 128 * 64;                // [128][64] swizzled
    uint16_t* Ct = smem;
    int t = threadIdx.x;
    int w = t >> 6, lane = t & 63;
    int row0 = blockIdx.x * BM;
    int mrow = (w >> 1) * 64, ncol = (w & 1) * 64;

    // per-lane staging indices (d = rep*256 + t): ar = row/col, akc = 16B chunk
    int ar[4], swz[4];
#pragma unroll
    for (int rep = 0; rep < 4; rep++) {
        int d = rep * 256 + t;
        int a = d >> 3, kc = d & 7;
        ar[rep] = a;
        swz[rep] = (kc * 8) ^ ((a & 7) << 3);      // u16 offset within 64-u16 half-row
    }

    f32x4 acc[4][4];
#pragma unroll
    for (int i = 0; i < 4; i++)
#pragma unroll
        for (int j = 0; j < 4; j++) acc[i][j] = (f32x4){0.f, 0.f, 0.f, 0.f};

    for (int k0 = 0; k0 < Kdim; k0 += BKS) {
        // stage A,B tiles via direct DMA (no bounds: OOB rows produce garbage
        // C rows that are never stored; addresses stay inside the workspace)
        int slotbase = (k0 >> 7) * (int)0;         // placeholder to keep types simple
        (void)slotbase;
#pragma unroll
        for (int rep = 0; rep < 4; rep++) {
            int grow = row0 + ar[rep];
            const uint16_t* ga = A + (size_t)(k0 >> 7) * sstride
                                 + (size_t)grow * 128 + (k0 & 64) + swz[rep];
            uint16_t* la = As + (size_t)(rep * 256 + (t & ~63)) * 8;
            dma16(ga, la, lane);
            const uint16_t* gb = Bt + (size_t)ar[rep] * Kdim + k0 + swz[rep];
            uint16_t* lb = Bs + (size_t)(rep * 256 + (t & ~63)) * 8;
            dma16(gb, lb, lane);
        }
        __syncthreads();                           // drains vmcnt(0): DMA complete
#pragma unroll
        for (int ks = 0; ks < BKS; ks += 32) {
            bf16x8 af[4], bfr[4];
#pragma unroll
            for (int i = 0; i < 4; i++) {
                int r = mrow + i * 16 + (lane & 15);
                int ko = (ks + (lane >> 4) * 8) ^ ((r & 7) << 3);
                af[i] = *(const bf16x8*)(&As[r * 64 + ko]);
            }
#pragma unroll
            for (int j = 0; j < 4; j++) {
                int c = ncol + j * 16 + (lane & 15);
                int ko = (ks + (lane >> 4) * 8) ^ ((c & 7) << 3);
                bfr[j] = *(const bf16x8*)(&Bs[c * 64 + ko]);
            }
#pragma unroll
            for (int i = 0; i < 4; i++)
#pragma unroll
                for (int j = 0; j < 4; j++)
                    acc[i][j] = __builtin_amdgcn_mfma_f32_16x16x32_bf16(af[i], bfr[j], acc[i][j], 0, 0, 0);
        }
        __syncthreads();
    }

    // bias + relu -> bf16 into LDS
#pragma unroll
    for (int j = 0; j < 4; j++) {
        int c = ncol + j * 16 + (lane & 15);
        float bv = bias[c];
#pragma unroll
        for (int i = 0; i < 4; i++) {
            int rloc = mrow + i * 16 + (lane >> 4) * 4;
#pragma unroll
            for (int r = 0; r < 4; r++) {
                float v = acc[i][j][r] + bv;
                v = v > 0.f ? v : 0.f;
                Ct[(rloc + r) * LDC + c] = f_to_bf16(v);
            }
        }
    }
    __syncthreads();

    if (out2b) {
#pragma unroll
        for (int rep = 0; rep < 8; rep++) {
            int d = rep * 256 + t;
            int r = d >> 4, c8 = (d & 15) * 8;
            int grow = row0 + r;
            if (grow < M) {
                bf16x8 v = *(const bf16x8*)(&Ct[r * LDC + c8]);
                *(bf16x8*)(out2b + (size_t)grow * 128 + c8) = v;
            }
        }
    }
    if (pooled) {
        // fused mean-pool accumulation: thread t covers feature f = t&127,
        // rows [ (t>>7)*64, +64 ); batch sorted -> segmented flush
        int f = t & 127, r0 = (t >> 7) * 64;
        float accp = 0.f;
        int curb = -1;
        for (int r = r0; r < r0 + 64; ++r) {
            int grow = row0 + r;
            if (grow >= M) break;
            int b = batch[grow];
            if (b != curb) {
                if (curb >= 0) atomicAdd(&pooled[curb * 128 + f], accp);
                accp = 0.f; curb = b;
            }
            accp += __uint_as_float(((uint32_t)Ct[r * LDC + f]) << 16);
        }
        if (curb >= 0) atomicAdd(&pooled[curb * 128 + f], accp);
    }
}

// ---------- final linear (counts via binary search on sorted batch) ----------
__global__ void k_final(const float* __restrict__ pooled, const int* __restrict__ batch,
                        const float* __restrict__ Wlin, const float* __restrict__ blin,
                        float* __restrict__ out, int N, int B_, int C_) {
    __shared__ int cnt[64];
    int t = threadIdx.x;
    if (t < B_) {
        auto lb = [&](int v) {
            int lo = 0, hi = N;
            while (lo < hi) {
                int mid = (lo + hi) >> 1;
                if (batch[mid] < v) lo = mid + 1; else hi = mid;
            }
            return lo;
        };
        cnt[t] = lb(t + 1) - lb(t);
    }
    __syncthreads();
    if (t < B_ * C_) {
        int b = t / C_, c = t % C_;
        float inv = 1.f / fmaxf((float)cnt[b], 1.f);
        float acc = blin[c];
        for (int f = 0; f < 128; ++f) acc += pooled[b * 128 + f] * inv * Wlin[f * C_ + c];
        out[t] = acc;
    }
}

// ---------- launch ----------
extern "C" void kernel_launch(void* const* d_in, const int* in_sizes, int n_in,
                              void* d_out, int out_size, void* d_ws, size_t ws_size,
                              hipStream_t stream) {
    const float* x    = (const float*)d_in[0];
    const int*   edge = (const int*)d_in[1];
    const int*   batch= (const int*)d_in[2];
    const float* lam  = (const float*)d_in[3];
    const float* W1   = (const float*)d_in[4];
    const float* b1   = (const float*)d_in[5];
    const float* W2   = (const float*)d_in[6];
    const float* b2   = (const float*)d_in[7];
    const float* Wlin = (const float*)d_in[8];
    const float* blin = (const float*)d_in[9];
    const int E  = in_sizes[1] / 2;
    const int N  = in_sizes[2];
    const int B_ = in_sizes[3];
    const int* row = edge;
    const int* col = edge + E;

    char* ws = (char*)d_ws;
    size_t off = 0;
    auto take = [&](size_t bytes) -> char* {
        char* p = ws + off;
        off = (off + bytes + 255) & ~(size_t)255;
        return p;
    };
    uint16_t* Txb    = (uint16_t*)take((size_t)5 * (N + 1) * 128 * 2);   // 64MB
    uint32_t* ew     = (uint32_t*)take(((size_t)E + 8 * (size_t)N) * 4);
    int*      deg    = (int*)take((size_t)N * 4);
    int*      offs   = (int*)take((size_t)(N + 1) * 4);
    float*    dis    = (float*)take((size_t)N * 4);
    float*    diag   = (float*)take((size_t)N * 4);
    uint4*    nh     = (uint4*)take((size_t)N * 16);
    uint16_t* Wt1    = (uint16_t*)take((size_t)128 * 640 * 2);
    uint16_t* Wt2    = (uint16_t*)take((size_t)128 * 640 * 2);
    float*    pooled = (float*)take((size_t)B_ * 128 * 4);   // 256-aligned size
    int*      bhist  = (int*)take(257 * 4);                  // contiguous after pooled
    int*      gbase  = (int*)take(257 * 4);
    int*      gcur   = (int*)take(257 * 4);
    const int nb = (N + 255) / 256;
    int*      psum   = (int*)take((size_t)nb * 4);
    // bout aliased into Txb slot-4 region (12.8MB >= E*4B; slot 4 is only
    // written by the 4th lhat pass, long after bout's last read in k_ew;
    // sentinel write of slot 4 (row N) is beyond bout's 3.2MB extent)
    uint32_t* bout   = (uint32_t*)((char*)Txb + (size_t)4 * (N + 1) * 256);

    // one fill covers pooled (B_*512 bytes, 256-multiple) + bhist
    hipMemsetAsync(pooled, 0, (size_t)B_ * 128 * 4 + 257 * 4, stream);

    const int nchunks = (E + BINCH - 1) / BINCH;

    k_pre1<<<1024, 256, 0, stream>>>(row, bhist, W1, Wt1, W2, Wt2, x, Txb, E, N);
    k_bscan<<<1, 256, 0, stream>>>(bhist, gbase, gcur, nb);
    k_bin<<<nchunks, 256, 0, stream>>>(row, col, gcur, bout, E);
    k_deg2<<<nb, 256, 0, stream>>>(bout, gbase, deg, psum, N);
    k_offs<<<nb, 256, 0, stream>>>(deg, psum, offs, batch, lam, dis, diag, nh, N, nb);
    k_ew<<<nb, 256, 0, stream>>>(bout, gbase, offs, dis, diag, ew, N);

    const int lblocks = (N + 3) / 4;
    const int gblocks = (N + BM - 1) / BM;
    const size_t ss = (size_t)(N + 1) * 128;               // u16 per slot

    // layer 1
    k_lhat<<<lblocks, 256, 0, stream>>>(Txb, nh, ew, N, 0, 1, 0, 1.f, 0);
    k_lhat<<<lblocks, 256, 0, stream>>>(Txb, nh, ew, N, 1, 2, 0, 2.f, 1);
    k_lhat<<<lblocks, 256, 0, stream>>>(Txb, nh, ew, N, 2, 3, 1, 2.f, 1);
    k_lhat<<<lblocks, 256, 0, stream>>>(Txb, nh, ew, N, 3, 4, 2, 2.f, 1);
    k_gemm<<<gblocks, 256, 0, stream>>>(Txb, ss, Wt1, b1,
                                        Txb /* slot 0 */, (float*)nullptr, batch, N, 640);

    // layer 2
    k_lhat<<<lblocks, 256, 0, stream>>>(Txb, nh, ew, N, 0, 1, 0, 1.f, 0);
    k_lhat<<<lblocks, 256, 0, stream>>>(Txb, nh, ew, N, 1, 2, 0, 2.f, 1);
    k_lhat<<<lblocks, 256, 0, stream>>>(Txb, nh, ew, N, 2, 3, 1, 2.f, 1);
    k_lhat<<<lblocks, 256, 0, stream>>>(Txb, nh, ew, N, 3, 4, 2, 2.f, 1);
    k_gemm<<<gblocks, 256, 0, stream>>>(Txb, ss, Wt2, b2,
                                        (uint16_t*)nullptr, pooled, batch, N, 640);

    k_final<<<1, 128, 0, stream>>>(pooled, batch, Wlin, blin, (float*)d_out, N, B_, 10);
}